// Round 9
// baseline (4838.311 us; speedup 1.0000x reference)
//
#include <hip/hip_runtime.h>
#include <hip/hip_bf16.h>
#include <math.h>

typedef __bf16 bf16_t;
typedef __bf16 bf16x8 __attribute__((ext_vector_type(8)));
typedef float  f32x4  __attribute__((ext_vector_type(4)));
typedef unsigned int uint32;
typedef unsigned char uint8;

// ---------------- workspace layout (bytes) ----------------
#define WS_WSP    0        // 1297 f32
#define WS_AH     5248     // 256 f32
#define WS_U527   6272     // 527 f32
#define WS_BIAS   8384     // 1 f32
#define WS_BIASG  8448     // 1024 f32
#define WS_WC     12544    // 393216 B: 12 units x 32KB (units 0-3 bf16 x-chunks, 4-11 fp8 h-pairs)

__device__ __forceinline__ float sigmoidf_fast(float x) {
    return 1.f / (1.f + __expf(-x));
}
__device__ __forceinline__ float tanhf_fast(float x) {
    return 1.f - 2.f / (1.f + __expf(2.f * x));
}

// ---------------- head/spatial weight composition (tiny) ----------------
__global__ void k_head(const float* __restrict__ sl_w, const float* __restrict__ sl_b,
                       const float* __restrict__ st_w, const float* __restrict__ st_b,
                       const float* __restrict__ seg_b,
                       const float* __restrict__ l1_w, const float* __restrict__ l1_b,
                       const float* __restrict__ l2_w, const float* __restrict__ l2_b,
                       const float* __restrict__ l4_w, const float* __restrict__ l4_b,
                       const float* __restrict__ l5_w, const float* __restrict__ l5_b,
                       const float* __restrict__ l6_w, const float* __restrict__ l6_b,
                       const float* __restrict__ l7_w, const float* __restrict__ l7_b,
                       float* __restrict__ wsp, float* __restrict__ ah,
                       float* __restrict__ u527_out, float* __restrict__ bias_out) {
    __shared__ float v2[128], v3[256], aa[384], u256[256], u527[527];
    __shared__ float red[8];
    const int t = threadIdx.x;   // 512 threads

    if (t < 128) { float s = 0.f; for (int i = 0; i < 128; ++i) s += l7_w[i] * l6_w[i*128 + t]; v2[t] = s; }
    __syncthreads();
    if (t < 256) { float s = 0.f; for (int i = 0; i < 128; ++i) s += v2[i] * l5_w[i*256 + t]; v3[t] = s; }
    __syncthreads();
    if (t < 384) { float s = 0.f; for (int i = 0; i < 256; ++i) s += v3[i] * l4_w[i*384 + t]; aa[t] = s; }
    __syncthreads();
    if (t < 256) { float s = 0.f; for (int i = 0; i < 128; ++i) s += aa[i] * l2_w[i*256 + t]; u256[t] = s; }
    if (t < 256) ah[t] = aa[128 + t];
    __syncthreads();
    for (int j = t; j < 527; j += 512) {
        float s = 0.f;
        for (int i = 0; i < 256; ++i) s += u256[i] * l1_w[i*527 + j];
        u527[j] = s; u527_out[j] = s;
    }
    __syncthreads();
    if (t < 4)              { float s = 0.f; for (int i = 0; i < 2; ++i) s += u527[i]     * sl_w[i*4  + t];      wsp[t] = s; }
    else if (t < 16)        { int c = t - 4;  float s = 0.f; for (int i = 0; i < 8; ++i) s += u527[2+i] * st_w[i*12 + c]; wsp[t] = s; }
    else if (t < 21)        { wsp[1292 + (t - 16)] = u527[522 + (t - 16)]; }
    float p = 0.f;
    if (t < 128) p += l7_w[t] * l6_b[t] + v2[t] * l5_b[t] + aa[t] * l2_b[t];
    if (t < 256) p += v3[t] * l4_b[t] + u256[t] * l1_b[t];
    if (t < 2)   p += u527[t] * sl_b[t];
    if (t < 8)   p += u527[2 + t] * st_b[t];
    p += u527[10 + t] * seg_b[t];
    p += __shfl_xor(p, 1);  p += __shfl_xor(p, 2);  p += __shfl_xor(p, 4);
    p += __shfl_xor(p, 8);  p += __shfl_xor(p, 16); p += __shfl_xor(p, 32);
    if ((t & 63) == 0) red[t >> 6] = p;
    __syncthreads();
    if (t == 0) {
        float s = l7_b[0];
        for (int i = 0; i < 8; ++i) s += red[i];
        *bias_out = s;
    }
}

__global__ void k_seg(const float* __restrict__ seg_w, const float* __restrict__ u527,
                      float* __restrict__ wsp) {
    int j = blockIdx.x * 256 + threadIdx.x;
    if (j >= 1276) return;
    float s = 0.f;
    for (int i = 0; i < 512; ++i) s += u527[10 + i] * seg_w[i*1276 + j];
    wsp[16 + j] = s;
}

// Mixed-precision streamed weights.
// Units 0..3 (x-part, bf16): unit = chunk ch = kk*2+half (kk=0,1), 32KB, frag j (0..31) at j*1024B.
// Units 4..11 (h-part, fp8 e4m3): unit u holds chunks hc=2(u-4) (bytes 0..16K) and hc+1 (16K..32K);
//   chunk: kk = 2+(hc>>1), half = hc&1; frag j (0..31) at j*512B (64 lanes x 8B).
// Frag identity (both): gidx = half*32 + j; wf = gidx>>3; rr = gidx&7; q = rr>>1; u = rr&1;
//   n = (q*16 + 2*wf + u)*16 + (lane&15); k = kk*32 + (lane>>4)*8 + e.
__global__ void k_wc3(const float* __restrict__ w_ih, const float* __restrict__ b_ih,
                      const float* __restrict__ w_hh, const float* __restrict__ b_hh,
                      uint8* __restrict__ wcB, float* __restrict__ biasg) {
    int idx = blockIdx.x * 256 + threadIdx.x;
    if (idx < 1024) biasg[idx] = b_ih[idx] + b_hh[idx];
    if (idx < 65536) {                        // x region: bf16 element index
        int ch = idx >> 14;                   // 0..3
        int r  = idx & 16383;
        int j  = r >> 9;
        int wi = r & 511;
        int lane = wi >> 3, e = wi & 7;
        int kk = ch >> 1, half = ch & 1;
        int gidx = half*32 + j;
        int wf = gidx >> 3, rr = gidx & 7, q = rr >> 1, uu = rr & 1;
        int n = (q*16 + 2*wf + uu)*16 + (lane & 15);
        int k = kk*32 + ((lane >> 4) << 3) + e;   // 0..63
        float v = (k < 56) ? w_ih[n*56 + k] : 0.f;
        ((bf16_t*)wcB)[idx] = (bf16_t)v;
    } else if (idx < 65536 + 262144) {        // h region: fp8 byte index
        int b  = idx - 65536;
        int hc = b >> 14;                     // 0..15
        int r  = b & 16383;
        int j  = r >> 9;
        int wi = r & 511;
        int lane = wi >> 3, e = wi & 7;
        int kk = 2 + (hc >> 1), half = hc & 1;
        int gidx = half*32 + j;
        int wf = gidx >> 3, rr = gidx & 7, q = rr >> 1, uu = rr & 1;
        int n = (q*16 + 2*wf + uu)*16 + (lane & 15);
        int k = kk*32 + ((lane >> 4) << 3) + e;   // 64..319
        float v = w_hh[n*256 + (k - 64)];
        uint32 pk = __builtin_amdgcn_cvt_pk_fp8_f32(v, 0.f, 0, false);
        wcB[131072 + b] = (uint8)(pk & 0xff);
    }
}

__global__ void k_spatial(const float* __restrict__ sp, const float* __restrict__ wsp,
                          const float* __restrict__ bias, float* __restrict__ out) {
    int row  = blockIdx.x * 4 + (threadIdx.x >> 6);
    int lane = threadIdx.x & 63;
    const float* rp = sp + (size_t)row * 1297;
    float s = 0.f;
    for (int k = lane; k < 1297; k += 64) s += rp[k] * wsp[k];
    s += __shfl_xor(s, 1);  s += __shfl_xor(s, 2);  s += __shfl_xor(s, 4);
    s += __shfl_xor(s, 8);  s += __shfl_xor(s, 16); s += __shfl_xor(s, 32);
    if (lane == 0) out[row] = s + bias[0];
}

// ---------------- LSTM v9: R7 skeleton, 12 phases, fp8 h-part ----------------
// 512 thr / 8 waves / 1 block/CU, 256 blocks x 64 rows. Per step: 12 units of 32KB
// through a 3-slot LDS ring (global_load_lds, counted vmcnt, barrier per phase).
// Units 0-3: bf16 x-chunks, half the waves compute. Units 4-11: fp8 h-pairs, ALL
// waves compute (wave's half at hf*16KB). A-side: Atx (bf16, swizzled) + Ah (fp8,
// swizzled 8B granules). Gates/c/h in regs; h stored fp8; epilogue from registers.
__launch_bounds__(512, 2)
__global__ void k_lstm(const float* __restrict__ temporal, const uint8* __restrict__ wcB,
                       const float* __restrict__ biasg, const float* __restrict__ ah,
                       float* __restrict__ out) {
    __shared__ char  Wlds[3 * 32768];    // 98304 B
    __shared__ char  Atx[64 * 128];      //  8192 B  bf16 x, 8x16B granules/row
    __shared__ char  Ahs[64 * 256];      // 16384 B  fp8 h, 32x8B granules/row
    __shared__ float Xf[64 * 56];        // 14336 B  (total 137216 B)

    const int tid  = threadIdx.x;
    const int lane = tid & 63;
    const int w    = tid >> 6;           // 0..7
    const int wg   = w & 3;
    const int hf   = w >> 2;
    const int l15  = lane & 15;
    const int l4q  = lane >> 4;          // 0..3
    const int row0 = blockIdx.x * 64;
    const int aswz = l15 & 7;

    float bias[8];
#pragma unroll
    for (int m = 0; m < 8; ++m)
        bias[m] = biasg[(m >> 1)*256 + 32*w + 16*(m & 1) + l15];
    float ahv[2];
#pragma unroll
    for (int u = 0; u < 2; ++u) ahv[u] = ah[32*w + 16*u + l15];

    // x DMA per-thread source offsets (bytes), as R7
    long xo0, xo1;
    {
        int b0 = (2*w + 0)*1024 + lane*16;
        int b1 = (2*w + 1)*1024 + lane*16;
        xo0 = (long)(b0/224)*21504 + (b0 % 224);
        xo1 = (long)(b1/224)*21504 + (b1 % 224);
    }
    const char* xbase = (const char*)(temporal + (size_t)row0 * 5376);

    auto stage_u = [&](int slot, int uu) {      // unit uu in [0,12): 32KB, 4 issues/wave
        const uint8* src = wcB + uu*32768 + w*4096 + lane*16;
        char* dst = Wlds + slot*32768 + w*4096 + lane*16;
#pragma unroll
        for (int i = 0; i < 4; ++i)
            __builtin_amdgcn_global_load_lds(
                (const __attribute__((address_space(1))) uint32*)(src + i*1024),
                (__attribute__((address_space(3))) uint32*)(dst + i*1024), 16, 0, 0);
    };
    auto stage_x = [&](int tt) {
        if (w < 7) {
            const char* s0 = xbase + xo0 + (size_t)tt*224;
            const char* s1 = xbase + xo1 + (size_t)tt*224;
            float* d0 = Xf + (2*w)*256 + lane*4;
            float* d1 = Xf + (2*w+1)*256 + lane*4;
            __builtin_amdgcn_global_load_lds((const __attribute__((address_space(1))) uint32*)s0,
                                             (__attribute__((address_space(3))) uint32*)d0, 16, 0, 0);
            __builtin_amdgcn_global_load_lds((const __attribute__((address_space(1))) uint32*)s1,
                                             (__attribute__((address_space(3))) uint32*)d1, 16, 0, 0);
        }
    };
    auto conv_x = [&]() {
        int xr = tid >> 3, xs = tid & 7;
        bf16x8 v = (bf16x8){0,0,0,0,0,0,0,0};
        if (xs < 7) {
            const float* xf = Xf + xr*56 + xs*8;
            f32x4 a = *reinterpret_cast<const f32x4*>(xf);
            f32x4 b = *reinterpret_cast<const f32x4*>(xf + 4);
#pragma unroll
            for (int e = 0; e < 4; ++e) { v[e] = (bf16_t)a[e]; v[4+e] = (bf16_t)b[e]; }
        }
        *reinterpret_cast<bf16x8*>(Atx + xr*128 + ((xs ^ (xr & 7)) << 4)) = v;
    };

    // ---- prologue: stage units 0,1 + x0; zero Ah; convert x0 ----
    stage_u(0, 0); stage_u(1, 1);
    stage_x(0);
    for (int i = tid; i < 4096; i += 512) reinterpret_cast<uint32*>(Ahs)[i] = 0u;
    asm volatile("s_waitcnt vmcnt(0)" ::: "memory");
    __builtin_amdgcn_s_barrier();
    conv_x();
    asm volatile("s_waitcnt lgkmcnt(0)" ::: "memory");
    __builtin_amdgcn_s_barrier();

    f32x4 cst[8];
#pragma unroll
    for (int i = 0; i < 8; ++i) cst[i] = (f32x4){0.f,0.f,0.f,0.f};
    float hreg[4][2][4];

#pragma unroll 1
    for (int t = 0; t < 96; ++t) {
        f32x4 acc[4][8];
#pragma unroll
        for (int rt = 0; rt < 4; ++rt)
#pragma unroll
            for (int m = 0; m < 8; ++m)
                acc[rt][m] = (f32x4){bias[m], bias[m], bias[m], bias[m]};

        int sl = 0;
#pragma unroll 1
        for (int c = 0; c < 12; ++c) {
            if (c == 1 || c == 2) asm volatile("s_waitcnt vmcnt(6)" ::: "memory");
            else                  asm volatile("s_waitcnt vmcnt(4)" ::: "memory");
            __builtin_amdgcn_s_barrier();
            {
                int s2 = sl + 2; if (s2 >= 3) s2 -= 3;
                int u2 = c + 2;  if (u2 >= 12) u2 -= 12;
                stage_u(s2, u2);
            }
            if (c == 0 && t < 95) stage_x(t + 1);

            if (c < 4) {
                if ((c & 1) == hf) {                    // bf16 x-chunk, half the waves
                    int kk = c >> 1;
                    bf16x8 af[4];
#pragma unroll
                    for (int rt = 0; rt < 4; ++rt) {
                        int ro = rt*16 + l15;
                        af[rt] = *reinterpret_cast<const bf16x8*>(
                            Atx + ro*128 + (((kk*4 + l4q) ^ aswz) << 4));
                    }
                    const char* bb = Wlds + sl*32768 + wg*8192 + lane*16;
#pragma unroll
                    for (int m = 0; m < 8; ++m) {
                        bf16x8 bv = *reinterpret_cast<const bf16x8*>(bb + m*1024);
#pragma unroll
                        for (int rt = 0; rt < 4; ++rt)
                            acc[rt][m] = __builtin_amdgcn_mfma_f32_16x16x32_bf16(
                                af[rt], bv, acc[rt][m], 0, 0, 0);
                    }
                }
            } else {                                    // fp8 h-pair, ALL waves
                int kk = c - 2;                         // 2..9
                int g0 = (kk - 2)*4 + l4q;              // granule 0..31
                long long af8[4];
#pragma unroll
                for (int rt = 0; rt < 4; ++rt) {
                    int ro = rt*16 + l15;
                    af8[rt] = *reinterpret_cast<const long long*>(
                        Ahs + ro*256 + ((g0 ^ ((ro & 7) << 2)) << 3));
                }
                const char* bb = Wlds + sl*32768 + hf*16384 + wg*4096 + lane*8;
#pragma unroll
                for (int m = 0; m < 8; ++m) {
                    long long bv = *reinterpret_cast<const long long*>(bb + m*512);
#pragma unroll
                    for (int rt = 0; rt < 4; ++rt)
                        acc[rt][m] = __builtin_amdgcn_mfma_f32_16x16x32_fp8_fp8(
                            af8[rt], bv, acc[rt][m], 0, 0, 0);
                }
            }
            sl = sl + 1; if (sl >= 3) sl -= 3;
        }

        // ---- gates -> c, h (regs only) ----
#pragma unroll
        for (int rt = 0; rt < 4; ++rt)
#pragma unroll
            for (int u = 0; u < 2; ++u)
#pragma unroll
                for (int e = 0; e < 4; ++e) {
                    float ig = sigmoidf_fast(acc[rt][0+u][e]);
                    float fg = sigmoidf_fast(acc[rt][2+u][e]);
                    float gt = tanhf_fast  (acc[rt][4+u][e]);
                    float og = sigmoidf_fast(acc[rt][6+u][e]);
                    float cn = fg * cst[rt*2+u][e] + ig * gt;
                    cst[rt*2+u][e] = cn;
                    hreg[rt][u][e] = og * tanhf_fast(cn);
                }

        __builtin_amdgcn_s_barrier();     // A: all LDS reads of this step done

        // ---- write h(t) as fp8 into Ahs (swizzled); convert x(t+1) ----
#pragma unroll
        for (int rt = 0; rt < 4; ++rt)
#pragma unroll
            for (int u = 0; u < 2; ++u) {
                int col = 32*w + 16*u + l15;
                int gq  = col >> 3, c7 = col & 7;
#pragma unroll
                for (int e = 0; e < 4; ++e) {
                    int ro = 16*rt + l4q*4 + e;
                    uint32 pk = __builtin_amdgcn_cvt_pk_fp8_f32(hreg[rt][u][e], 0.f, 0, false);
                    Ahs[ro*256 + ((gq ^ ((ro & 7) << 2)) << 3) + c7] = (char)(pk & 0xff);
                }
            }
        if (t < 95) {
            asm volatile("s_waitcnt vmcnt(8)" ::: "memory");   // x landed (units 0',1' may fly)
            conv_x();
        }
        asm volatile("s_waitcnt lgkmcnt(0)" ::: "memory");
        __builtin_amdgcn_s_barrier();     // B
    }

    // ---- epilogue: out[row] += ah . h_T[row], deterministic via LDS ----
    {
#pragma unroll
        for (int rt = 0; rt < 4; ++rt)
#pragma unroll
            for (int e = 0; e < 4; ++e) {
                float p = ahv[0]*hreg[rt][0][e] + ahv[1]*hreg[rt][1][e];
                p += __shfl_xor(p, 1); p += __shfl_xor(p, 2);
                p += __shfl_xor(p, 4); p += __shfl_xor(p, 8);
                if (l15 == 0) Xf[w*64 + 16*rt + l4q*4 + e] = p;
            }
        __syncthreads();
        if (tid < 64) {
            float s = 0.f;
#pragma unroll
            for (int wv = 0; wv < 8; ++wv) s += Xf[wv*64 + tid];
            out[row0 + tid] += s;
        }
    }
}

// ---------------- launch ----------------
extern "C" void kernel_launch(void* const* d_in, const int* in_sizes, int n_in,
                              void* d_out, int out_size, void* d_ws, size_t ws_size,
                              hipStream_t stream) {
    const float* spatial  = (const float*)d_in[0];
    const float* temporal = (const float*)d_in[1];
    const float* sl_w = (const float*)d_in[2];  const float* sl_b = (const float*)d_in[3];
    const float* st_w = (const float*)d_in[4];  const float* st_b = (const float*)d_in[5];
    const float* seg_w = (const float*)d_in[6]; const float* seg_b = (const float*)d_in[7];
    const float* l1_w = (const float*)d_in[8];  const float* l1_b = (const float*)d_in[9];
    const float* l2_w = (const float*)d_in[10]; const float* l2_b = (const float*)d_in[11];
    const float* w_ih = (const float*)d_in[12]; const float* b_ih = (const float*)d_in[13];
    const float* w_hh = (const float*)d_in[14]; const float* b_hh = (const float*)d_in[15];
    const float* l4_w = (const float*)d_in[16]; const float* l4_b = (const float*)d_in[17];
    const float* l5_w = (const float*)d_in[18]; const float* l5_b = (const float*)d_in[19];
    const float* l6_w = (const float*)d_in[20]; const float* l6_b = (const float*)d_in[21];
    const float* l7_w = (const float*)d_in[22]; const float* l7_b = (const float*)d_in[23];

    char* ws = (char*)d_ws;
    float*  wsp   = (float*)(ws + WS_WSP);
    float*  ah    = (float*)(ws + WS_AH);
    float*  u527  = (float*)(ws + WS_U527);
    float*  biasT = (float*)(ws + WS_BIAS);
    float*  biasg = (float*)(ws + WS_BIASG);
    uint8*  wcB   = (uint8*)(ws + WS_WC);

    float* out = (float*)d_out;

    hipLaunchKernelGGL(k_head, dim3(1), dim3(512), 0, stream,
                       sl_w, sl_b, st_w, st_b, seg_b, l1_w, l1_b, l2_w, l2_b,
                       l4_w, l4_b, l5_w, l5_b, l6_w, l6_b, l7_w, l7_b,
                       wsp, ah, u527, biasT);
    hipLaunchKernelGGL(k_seg, dim3(5), dim3(256), 0, stream, seg_w, u527, wsp);
    hipLaunchKernelGGL(k_wc3, dim3(1280), dim3(256), 0, stream,
                       w_ih, b_ih, w_hh, b_hh, wcB, biasg);
    hipLaunchKernelGGL(k_spatial, dim3(16384/4), dim3(256), 0, stream,
                       spatial, wsp, biasT, out);
    hipLaunchKernelGGL(k_lstm, dim3(256), dim3(512), 0, stream,
                       temporal, wcB, biasg, ah, out);
}

// Round 11
// 1827.116 us; speedup vs baseline: 2.6481x; 2.6481x over previous
//
#include <hip/hip_runtime.h>
#include <hip/hip_bf16.h>
#include <math.h>

typedef __bf16 bf16_t;
typedef float  f32x4  __attribute__((ext_vector_type(4)));
typedef unsigned int uint32;
typedef unsigned char uint8;
typedef long long ll_t;

// ---------------- workspace layout (bytes) ----------------
#define WS_WSP    0        // 1297 f32
#define WS_AH     5248     // 256 f32
#define WS_U527   6272     // 527 f32
#define WS_BIAS   8384     // 1 f32
#define WS_BIASG  8448     // 1024 f32
#define WS_WC     12544    // 327680 B fp8 weights: 10 units x 32KB

__device__ __forceinline__ float sigmoidf_fast(float x) {
    return 1.f / (1.f + __expf(-x));
}
__device__ __forceinline__ float tanhf_fast(float x) {
    return 1.f - 2.f / (1.f + __expf(2.f * x));
}

// ---------------- head/spatial weight composition (tiny) ----------------
__global__ void k_head(const float* __restrict__ sl_w, const float* __restrict__ sl_b,
                       const float* __restrict__ st_w, const float* __restrict__ st_b,
                       const float* __restrict__ seg_b,
                       const float* __restrict__ l1_w, const float* __restrict__ l1_b,
                       const float* __restrict__ l2_w, const float* __restrict__ l2_b,
                       const float* __restrict__ l4_w, const float* __restrict__ l4_b,
                       const float* __restrict__ l5_w, const float* __restrict__ l5_b,
                       const float* __restrict__ l6_w, const float* __restrict__ l6_b,
                       const float* __restrict__ l7_w, const float* __restrict__ l7_b,
                       float* __restrict__ wsp, float* __restrict__ ah,
                       float* __restrict__ u527_out, float* __restrict__ bias_out) {
    __shared__ float v2[128], v3[256], aa[384], u256[256], u527[527];
    __shared__ float red[8];
    const int t = threadIdx.x;   // 512 threads

    if (t < 128) { float s = 0.f; for (int i = 0; i < 128; ++i) s += l7_w[i] * l6_w[i*128 + t]; v2[t] = s; }
    __syncthreads();
    if (t < 256) { float s = 0.f; for (int i = 0; i < 128; ++i) s += v2[i] * l5_w[i*256 + t]; v3[t] = s; }
    __syncthreads();
    if (t < 384) { float s = 0.f; for (int i = 0; i < 256; ++i) s += v3[i] * l4_w[i*384 + t]; aa[t] = s; }
    __syncthreads();
    if (t < 256) { float s = 0.f; for (int i = 0; i < 128; ++i) s += aa[i] * l2_w[i*256 + t]; u256[t] = s; }
    if (t < 256) ah[t] = aa[128 + t];
    __syncthreads();
    for (int j = t; j < 527; j += 512) {
        float s = 0.f;
        for (int i = 0; i < 256; ++i) s += u256[i] * l1_w[i*527 + j];
        u527[j] = s; u527_out[j] = s;
    }
    __syncthreads();
    if (t < 4)              { float s = 0.f; for (int i = 0; i < 2; ++i) s += u527[i]     * sl_w[i*4  + t];      wsp[t] = s; }
    else if (t < 16)        { int c = t - 4;  float s = 0.f; for (int i = 0; i < 8; ++i) s += u527[2+i] * st_w[i*12 + c]; wsp[t] = s; }
    else if (t < 21)        { wsp[1292 + (t - 16)] = u527[522 + (t - 16)]; }
    float p = 0.f;
    if (t < 128) p += l7_w[t] * l6_b[t] + v2[t] * l5_b[t] + aa[t] * l2_b[t];
    if (t < 256) p += v3[t] * l4_b[t] + u256[t] * l1_b[t];
    if (t < 2)   p += u527[t] * sl_b[t];
    if (t < 8)   p += u527[2 + t] * st_b[t];
    p += u527[10 + t] * seg_b[t];
    p += __shfl_xor(p, 1);  p += __shfl_xor(p, 2);  p += __shfl_xor(p, 4);
    p += __shfl_xor(p, 8);  p += __shfl_xor(p, 16); p += __shfl_xor(p, 32);
    if ((t & 63) == 0) red[t >> 6] = p;
    __syncthreads();
    if (t == 0) {
        float s = l7_b[0];
        for (int i = 0; i < 8; ++i) s += red[i];
        *bias_out = s;
    }
}

__global__ void k_seg(const float* __restrict__ seg_w, const float* __restrict__ u527,
                      float* __restrict__ wsp) {
    int j = blockIdx.x * 256 + threadIdx.x;
    if (j >= 1276) return;
    float s = 0.f;
    for (int i = 0; i < 512; ++i) s += u527[10 + i] * seg_w[i*1276 + j];
    wsp[16 + j] = s;
}

// fp8 weights, W as the MFMA A-operand.
// Unit kk (K-slice of 32) = 32KB at kk*32768. Wave w region: w*4096.
// Frag f = ht*4 + q at f*512; lane*8 + e. A-frag: row = gate-col (lane&15),
// k = (lane>>4)*8 + e. n = q*256 + 32w + 16ht + (lane&15); k_glob = kk*32 + klocal.
__global__ void k_wcq(const float* __restrict__ w_ih, const float* __restrict__ b_ih,
                      const float* __restrict__ w_hh, const float* __restrict__ b_hh,
                      uint8* __restrict__ wcq, float* __restrict__ biasg) {
    int idx = blockIdx.x * 256 + threadIdx.x;
    if (idx < 1024) biasg[idx] = b_ih[idx] + b_hh[idx];
    if (idx < 327680) {
        int kk = idx >> 15;
        int r  = idx & 32767;
        int w  = r >> 12;
        int r2 = r & 4095;
        int f  = r2 >> 9;
        int ht = f >> 2, q = f & 3;
        int r3 = r2 & 511;
        int lane = r3 >> 3, e = r3 & 7;
        int n = q*256 + 32*w + 16*ht + (lane & 15);
        int k = kk*32 + ((lane >> 4) << 3) + e;
        float v = 0.f;
        if (k < 56)       v = w_ih[n*56 + k];
        else if (k >= 64) v = w_hh[n*256 + (k - 64)];
        uint32 pk = __builtin_amdgcn_cvt_pk_fp8_f32(v, 0.f, 0, false);
        wcq[idx] = (uint8)(pk & 0xff);
    }
}

__global__ void k_spatial(const float* __restrict__ sp, const float* __restrict__ wsp,
                          const float* __restrict__ bias, float* __restrict__ out) {
    int row  = blockIdx.x * 4 + (threadIdx.x >> 6);
    int lane = threadIdx.x & 63;
    const float* rp = sp + (size_t)row * 1297;
    float s = 0.f;
    for (int k = lane; k < 1297; k += 64) s += rp[k] * wsp[k];
    s += __shfl_xor(s, 1);  s += __shfl_xor(s, 2);  s += __shfl_xor(s, 4);
    s += __shfl_xor(s, 8);  s += __shfl_xor(s, 16); s += __shfl_xor(s, 32);
    if (lane == 0) out[row] = s + bias[0];
}

// ---------------- LSTM v10b: all-fp8, swapped operands, self-staged ring ----------------
// 512 thr / 8 waves / 1 block/CU, 256 blocks x 64 rows. Per step: 10 units of 32KB fp8
// through a 3-slot ring; each wave stages ITS OWN 4KB per unit (slot reuse is ordered by
// the wave's own vmcnt) -> barrier only every 2 phases + 2 A-tile barriers.
// MFMA: A = W (row=gate-col), B = activations (col=batch-row). D elements per thread =
// 4 adjacent hidden dims of one batch row -> packed b32 h-writeback, thread-local gates.
// At: fp8 [64 rows][328]: k 0..55 x, 56..63 zero-pad, 64..319 h.
__launch_bounds__(512, 2)
__global__ void k_lstm(const float* __restrict__ temporal, const uint8* __restrict__ wcq,
                       const float* __restrict__ biasg, const float* __restrict__ ah,
                       float* __restrict__ out) {
    __shared__ char  Ring[3 * 32768];   // 98304 B, per-wave regions w*4096
    __shared__ char  At[64 * 328];      // 20992 B
    __shared__ float Xf[64 * 56];       // 14336 B
    __shared__ char  Xd[2048];          //  2048 B (wave-7 vmcnt-balancing dummy)

    const int tid  = threadIdx.x;
    const int lane = tid & 63;
    const int w    = tid >> 6;          // 0..7
    const int l15  = lane & 15;
    const int l4q  = lane >> 4;         // 0..3
    const int row0 = blockIdx.x * 64;

    f32x4 bias[2][4];                   // [ht][q]
#pragma unroll
    for (int ht = 0; ht < 2; ++ht)
#pragma unroll
        for (int q = 0; q < 4; ++q)
            bias[ht][q] = *reinterpret_cast<const f32x4*>(biasg + q*256 + 32*w + 16*ht + 4*l4q);
    f32x4 ahv[2];
#pragma unroll
    for (int ht = 0; ht < 2; ++ht)
        ahv[ht] = *reinterpret_cast<const f32x4*>(ah + 32*w + 16*ht + 4*l4q);

    // x staging source offsets (R7 mapping): wave w covers Xf bytes [2w*1024, 2w*1024+2048)
    long xo0, xo1;
    {
        int b0 = (2*w + 0)*1024 + lane*16;
        int b1 = (2*w + 1)*1024 + lane*16;
        xo0 = (long)(b0/224)*21504 + (b0 % 224);
        xo1 = (long)(b1/224)*21504 + (b1 % 224);
    }
    const char* xbase = (const char*)(temporal + (size_t)row0 * 5376);

    auto stage_w = [&](int slot, int uu) {
        const uint8* src = wcq + uu*32768 + w*4096 + lane*16;
        char* dst = Ring + slot*32768 + w*4096 + lane*16;
#pragma unroll
        for (int i = 0; i < 4; ++i)
            __builtin_amdgcn_global_load_lds(
                (const __attribute__((address_space(1))) uint32*)(src + i*1024),
                (__attribute__((address_space(3))) uint32*)(dst + i*1024), 16, 0, 0);
    };
    auto stage_x = [&](int tt) {
        if (w < 7) {
            const char* s0 = xbase + xo0 + (size_t)tt*224;
            const char* s1 = xbase + xo1 + (size_t)tt*224;
            float* d0 = Xf + (2*w)*256 + lane*4;
            float* d1 = Xf + (2*w+1)*256 + lane*4;
            __builtin_amdgcn_global_load_lds((const __attribute__((address_space(1))) uint32*)s0,
                                             (__attribute__((address_space(3))) uint32*)d0, 16, 0, 0);
            __builtin_amdgcn_global_load_lds((const __attribute__((address_space(1))) uint32*)s1,
                                             (__attribute__((address_space(3))) uint32*)d1, 16, 0, 0);
        } else {   // keep vmcnt uniform across waves
            const char* s0 = xbase + lane*16;
            __builtin_amdgcn_global_load_lds((const __attribute__((address_space(1))) uint32*)s0,
                                             (__attribute__((address_space(3))) uint32*)(Xd + lane*16), 16, 0, 0);
            __builtin_amdgcn_global_load_lds((const __attribute__((address_space(1))) uint32*)(s0 + 1024),
                                             (__attribute__((address_space(3))) uint32*)(Xd + 1024 + lane*16), 16, 0, 0);
        }
    };
    auto conv_x = [&]() {               // Xf (f32) -> At fp8, rows tid>>3, 8 cols each
        int xr = tid >> 3, xs = tid & 7;
        if (xs < 7) {
            const float* xf = Xf + xr*56 + xs*8;
            f32x4 a = *reinterpret_cast<const f32x4*>(xf);
            f32x4 b = *reinterpret_cast<const f32x4*>(xf + 4);
            uint32 lo = __builtin_amdgcn_cvt_pk_fp8_f32(a[0], a[1], 0, false);
            lo = __builtin_amdgcn_cvt_pk_fp8_f32(a[2], a[3], lo, true);
            uint32 hi = __builtin_amdgcn_cvt_pk_fp8_f32(b[0], b[1], 0, false);
            hi = __builtin_amdgcn_cvt_pk_fp8_f32(b[2], b[3], hi, true);
            uint32* p = reinterpret_cast<uint32*>(At + xr*328 + xs*8);
            p[0] = lo; p[1] = hi;
        } else {
            uint32* p = reinterpret_cast<uint32*>(At + xr*328 + 56);
            p[0] = 0u; p[1] = 0u;       // zero pad k=56..63
        }
    };

    // ---- prologue: x0 + units 0,1; zero At; convert x0 ----
    stage_x(0);
    stage_w(0, 0); stage_w(1, 1);
    for (int i = tid; i < 1312; i += 512)
        *reinterpret_cast<f32x4*>(At + i*16) = (f32x4){0.f,0.f,0.f,0.f};
    asm volatile("s_waitcnt vmcnt(0)" ::: "memory");
    __builtin_amdgcn_s_barrier();
    conv_x();
    asm volatile("s_waitcnt lgkmcnt(0)" ::: "memory");
    __builtin_amdgcn_s_barrier();

    f32x4 cst[4][2];                    // c state [rt][ht]
    f32x4 hv[4][2];                     // h(t) values, carried to epilogue
#pragma unroll
    for (int rt = 0; rt < 4; ++rt)
#pragma unroll
        for (int ht = 0; ht < 2; ++ht) cst[rt][ht] = (f32x4){0.f,0.f,0.f,0.f};

    int sl = 0;                         // ring slot of current unit (continuous mod 3)
#pragma unroll 1
    for (int t = 0; t < 96; ++t) {
        f32x4 acc[4][2][4];             // [rt][ht][q]
#pragma unroll
        for (int rt = 0; rt < 4; ++rt)
#pragma unroll
            for (int ht = 0; ht < 2; ++ht)
#pragma unroll
                for (int q = 0; q < 4; ++q)
                    acc[rt][ht][q] = bias[ht][q];

#pragma unroll 1
        for (int c = 0; c < 10; ++c) {
            if ((c & 1) == 0 && c != 0) __builtin_amdgcn_s_barrier();
            if (c == 1 || c == 2) asm volatile("s_waitcnt vmcnt(6)" ::: "memory");
            else                  asm volatile("s_waitcnt vmcnt(4)" ::: "memory");

            {   // 2-deep prefetch: unit c+2 -> slot (sl+2)%3
                int s2 = sl + 2; if (s2 >= 3) s2 -= 3;
                int u2 = c + 2;  if (u2 >= 10) u2 -= 10;
                stage_w(s2, u2);
            }
            if (c == 0) stage_x(t < 95 ? t + 1 : 95);

            const char* wb = Ring + sl*32768 + w*4096 + lane*8;
            ll_t Bv[4];
#pragma unroll
            for (int rt = 0; rt < 4; ++rt)
                Bv[rt] = *reinterpret_cast<const ll_t*>(At + (rt*16 + l15)*328 + c*32 + l4q*8);
#pragma unroll
            for (int ht = 0; ht < 2; ++ht)
#pragma unroll
                for (int q = 0; q < 4; ++q) {
                    ll_t Af = *reinterpret_cast<const ll_t*>(wb + (ht*4 + q)*512);
#pragma unroll
                    for (int rt = 0; rt < 4; ++rt)
                        acc[rt][ht][q] = __builtin_amdgcn_mfma_f32_16x16x32_fp8_fp8(
                            Af, Bv[rt], acc[rt][ht][q], 0, 0, 0);
                }
            sl = sl + 1; if (sl >= 3) sl -= 3;
        }

        // ---- gates -> c, h (thread-local; e = adjacent hidden dims, one batch row) ----
#pragma unroll
        for (int rt = 0; rt < 4; ++rt)
#pragma unroll
            for (int ht = 0; ht < 2; ++ht)
#pragma unroll
                for (int e = 0; e < 4; ++e) {
                    float ig = sigmoidf_fast(acc[rt][ht][0][e]);
                    float fg = sigmoidf_fast(acc[rt][ht][1][e]);
                    float gt = tanhf_fast  (acc[rt][ht][2][e]);
                    float og = sigmoidf_fast(acc[rt][ht][3][e]);
                    float cn = fg * cst[rt][ht][e] + ig * gt;
                    cst[rt][ht][e] = cn;
                    hv[rt][ht][e] = og * tanhf_fast(cn);
                }

        if (t < 95) {
            __builtin_amdgcn_s_barrier();        // A: all At reads done
#pragma unroll
            for (int rt = 0; rt < 4; ++rt)
#pragma unroll
                for (int ht = 0; ht < 2; ++ht) {
                    uint32 pk = __builtin_amdgcn_cvt_pk_fp8_f32(hv[rt][ht][0], hv[rt][ht][1], 0, false);
                    pk = __builtin_amdgcn_cvt_pk_fp8_f32(hv[rt][ht][2], hv[rt][ht][3], pk, true);
                    *reinterpret_cast<uint32*>(
                        At + (rt*16 + l15)*328 + 64 + 32*w + 16*ht + 4*l4q) = pk;
                }
            conv_x();
            asm volatile("s_waitcnt lgkmcnt(0)" ::: "memory");
            __builtin_amdgcn_s_barrier();        // B: writes visible
        }
    }

    // ---- epilogue: out[row] += ah . h_T[row] ----
    {
        float part[4];
#pragma unroll
        for (int rt = 0; rt < 4; ++rt) {
            float s = 0.f;
#pragma unroll
            for (int ht = 0; ht < 2; ++ht)
#pragma unroll
                for (int e = 0; e < 4; ++e)
                    s += ahv[ht][e] * hv[rt][ht][e];
            s += __shfl_xor(s, 16);
            s += __shfl_xor(s, 32);
            part[rt] = s;
        }
        __builtin_amdgcn_s_barrier();
        float* sc = reinterpret_cast<float*>(Ring);
        if (l4q == 0)
#pragma unroll
            for (int rt = 0; rt < 4; ++rt)
                sc[w*64 + rt*16 + l15] = part[rt];
        asm volatile("s_waitcnt lgkmcnt(0)" ::: "memory");
        __builtin_amdgcn_s_barrier();
        if (tid < 64) {
            float s = 0.f;
#pragma unroll
            for (int wv = 0; wv < 8; ++wv) s += sc[wv*64 + tid];
            out[row0 + tid] += s;
        }
    }
}

// ---------------- launch ----------------
extern "C" void kernel_launch(void* const* d_in, const int* in_sizes, int n_in,
                              void* d_out, int out_size, void* d_ws, size_t ws_size,
                              hipStream_t stream) {
    const float* spatial  = (const float*)d_in[0];
    const float* temporal = (const float*)d_in[1];
    const float* sl_w = (const float*)d_in[2];  const float* sl_b = (const float*)d_in[3];
    const float* st_w = (const float*)d_in[4];  const float* st_b = (const float*)d_in[5];
    const float* seg_w = (const float*)d_in[6]; const float* seg_b = (const float*)d_in[7];
    const float* l1_w = (const float*)d_in[8];  const float* l1_b = (const float*)d_in[9];
    const float* l2_w = (const float*)d_in[10]; const float* l2_b = (const float*)d_in[11];
    const float* w_ih = (const float*)d_in[12]; const float* b_ih = (const float*)d_in[13];
    const float* w_hh = (const float*)d_in[14]; const float* b_hh = (const float*)d_in[15];
    const float* l4_w = (const float*)d_in[16]; const float* l4_b = (const float*)d_in[17];
    const float* l5_w = (const float*)d_in[18]; const float* l5_b = (const float*)d_in[19];
    const float* l6_w = (const float*)d_in[20]; const float* l6_b = (const float*)d_in[21];
    const float* l7_w = (const float*)d_in[22]; const float* l7_b = (const float*)d_in[23];

    char* ws = (char*)d_ws;
    float*  wsp   = (float*)(ws + WS_WSP);
    float*  ah    = (float*)(ws + WS_AH);
    float*  u527  = (float*)(ws + WS_U527);
    float*  biasT = (float*)(ws + WS_BIAS);
    float*  biasg = (float*)(ws + WS_BIASG);
    uint8*  wcq   = (uint8*)(ws + WS_WC);

    float* out = (float*)d_out;

    hipLaunchKernelGGL(k_head, dim3(1), dim3(512), 0, stream,
                       sl_w, sl_b, st_w, st_b, seg_b, l1_w, l1_b, l2_w, l2_b,
                       l4_w, l4_b, l5_w, l5_b, l6_w, l6_b, l7_w, l7_b,
                       wsp, ah, u527, biasT);
    hipLaunchKernelGGL(k_seg, dim3(5), dim3(256), 0, stream, seg_w, u527, wsp);
    hipLaunchKernelGGL(k_wcq, dim3(1280), dim3(256), 0, stream,
                       w_ih, b_ih, w_hh, b_hh, wcq, biasg);
    hipLaunchKernelGGL(k_spatial, dim3(16384/4), dim3(256), 0, stream,
                       spatial, wsp, biasT, out);
    hipLaunchKernelGGL(k_lstm, dim3(256), dim3(512), 0, stream,
                       temporal, wcq, biasg, ah, out);
}

// Round 12
// 1699.664 us; speedup vs baseline: 2.8466x; 1.0750x over previous
//
#include <hip/hip_runtime.h>
#include <hip/hip_bf16.h>
#include <math.h>

typedef __bf16 bf16_t;
typedef float  f32x4  __attribute__((ext_vector_type(4)));
typedef unsigned int uint32;
typedef unsigned char uint8;
typedef long long ll_t;
typedef long long ll2 __attribute__((ext_vector_type(2)));

// ---------------- workspace layout (bytes) ----------------
#define WS_WSP    0        // 1297 f32
#define WS_AH     5248     // 256 f32
#define WS_U527   6272     // 527 f32
#define WS_BIAS   8384     // 1 f32
#define WS_BIASG  8448     // 1024 f32
#define WS_WC     12544    // 327680 B fp8 weights: 10 units x 32KB

__device__ __forceinline__ float sigmoidf_fast(float x) {
    return 1.f / (1.f + __expf(-x));
}
__device__ __forceinline__ float tanhf_fast(float x) {
    return 1.f - 2.f / (1.f + __expf(2.f * x));
}

// ---------------- head/spatial weight composition (tiny) ----------------
__global__ void k_head(const float* __restrict__ sl_w, const float* __restrict__ sl_b,
                       const float* __restrict__ st_w, const float* __restrict__ st_b,
                       const float* __restrict__ seg_b,
                       const float* __restrict__ l1_w, const float* __restrict__ l1_b,
                       const float* __restrict__ l2_w, const float* __restrict__ l2_b,
                       const float* __restrict__ l4_w, const float* __restrict__ l4_b,
                       const float* __restrict__ l5_w, const float* __restrict__ l5_b,
                       const float* __restrict__ l6_w, const float* __restrict__ l6_b,
                       const float* __restrict__ l7_w, const float* __restrict__ l7_b,
                       float* __restrict__ wsp, float* __restrict__ ah,
                       float* __restrict__ u527_out, float* __restrict__ bias_out) {
    __shared__ float v2[128], v3[256], aa[384], u256[256], u527[527];
    __shared__ float red[8];
    const int t = threadIdx.x;   // 512 threads

    if (t < 128) { float s = 0.f; for (int i = 0; i < 128; ++i) s += l7_w[i] * l6_w[i*128 + t]; v2[t] = s; }
    __syncthreads();
    if (t < 256) { float s = 0.f; for (int i = 0; i < 128; ++i) s += v2[i] * l5_w[i*256 + t]; v3[t] = s; }
    __syncthreads();
    if (t < 384) { float s = 0.f; for (int i = 0; i < 256; ++i) s += v3[i] * l4_w[i*384 + t]; aa[t] = s; }
    __syncthreads();
    if (t < 256) { float s = 0.f; for (int i = 0; i < 128; ++i) s += aa[i] * l2_w[i*256 + t]; u256[t] = s; }
    if (t < 256) ah[t] = aa[128 + t];
    __syncthreads();
    for (int j = t; j < 527; j += 512) {
        float s = 0.f;
        for (int i = 0; i < 256; ++i) s += u256[i] * l1_w[i*527 + j];
        u527[j] = s; u527_out[j] = s;
    }
    __syncthreads();
    if (t < 4)              { float s = 0.f; for (int i = 0; i < 2; ++i) s += u527[i]     * sl_w[i*4  + t];      wsp[t] = s; }
    else if (t < 16)        { int c = t - 4;  float s = 0.f; for (int i = 0; i < 8; ++i) s += u527[2+i] * st_w[i*12 + c]; wsp[t] = s; }
    else if (t < 21)        { wsp[1292 + (t - 16)] = u527[522 + (t - 16)]; }
    float p = 0.f;
    if (t < 128) p += l7_w[t] * l6_b[t] + v2[t] * l5_b[t] + aa[t] * l2_b[t];
    if (t < 256) p += v3[t] * l4_b[t] + u256[t] * l1_b[t];
    if (t < 2)   p += u527[t] * sl_b[t];
    if (t < 8)   p += u527[2 + t] * st_b[t];
    p += u527[10 + t] * seg_b[t];
    p += __shfl_xor(p, 1);  p += __shfl_xor(p, 2);  p += __shfl_xor(p, 4);
    p += __shfl_xor(p, 8);  p += __shfl_xor(p, 16); p += __shfl_xor(p, 32);
    if ((t & 63) == 0) red[t >> 6] = p;
    __syncthreads();
    if (t == 0) {
        float s = l7_b[0];
        for (int i = 0; i < 8; ++i) s += red[i];
        *bias_out = s;
    }
}

__global__ void k_seg(const float* __restrict__ seg_w, const float* __restrict__ u527,
                      float* __restrict__ wsp) {
    int j = blockIdx.x * 256 + threadIdx.x;
    if (j >= 1276) return;
    float s = 0.f;
    for (int i = 0; i < 512; ++i) s += u527[10 + i] * seg_w[i*1276 + j];
    wsp[16 + j] = s;
}

// fp8 weights, W as the MFMA A-operand, PAIR-PACKED for ds_read_b128.
// Unit kk = 32KB at kk*32768; wave region w*4096; issue j (0..3) at j*1024;
// lane block lane*16 (16 B): bytes 0..7 = frag f=2j, bytes 8..15 = frag f=2j+1.
// Frag f = ht*4+q: n = q*256 + 32w + 16ht + (lane&15); k = kk*32 + (lane>>4)*8 + e.
__global__ void k_wcq(const float* __restrict__ w_ih, const float* __restrict__ b_ih,
                      const float* __restrict__ w_hh, const float* __restrict__ b_hh,
                      uint8* __restrict__ wcq, float* __restrict__ biasg) {
    int idx = blockIdx.x * 256 + threadIdx.x;
    if (idx < 1024) biasg[idx] = b_ih[idx] + b_hh[idx];
    if (idx < 327680) {
        int kk = idx >> 15;
        int r  = idx & 32767;
        int w  = r >> 12;
        int r2 = r & 4095;
        int j  = r2 >> 10;
        int r3 = r2 & 1023;
        int lane = r3 >> 4;
        int b  = r3 & 15;
        int f  = 2*j + (b >> 3);
        int e  = b & 7;
        int ht = f >> 2, q = f & 3;
        int n = q*256 + 32*w + 16*ht + (lane & 15);
        int k = kk*32 + ((lane >> 4) << 3) + e;
        float v = 0.f;
        if (k < 56)       v = w_ih[n*56 + k];
        else if (k >= 64) v = w_hh[n*256 + (k - 64)];
        uint32 pk = __builtin_amdgcn_cvt_pk_fp8_f32(v, 0.f, 0, false);
        wcq[idx] = (uint8)(pk & 0xff);
    }
}

__global__ void k_spatial(const float* __restrict__ sp, const float* __restrict__ wsp,
                          const float* __restrict__ bias, float* __restrict__ out) {
    int row  = blockIdx.x * 4 + (threadIdx.x >> 6);
    int lane = threadIdx.x & 63;
    const float* rp = sp + (size_t)row * 1297;
    float s = 0.f;
    for (int k = lane; k < 1297; k += 64) s += rp[k] * wsp[k];
    s += __shfl_xor(s, 1);  s += __shfl_xor(s, 2);  s += __shfl_xor(s, 4);
    s += __shfl_xor(s, 8);  s += __shfl_xor(s, 16); s += __shfl_xor(s, 32);
    if (lane == 0) out[row] = s + bias[0];
}

// ---------------- LSTM v11: barrier-minimal fp8 stream ----------------
// 512 thr / 8 waves / 1 block/CU, 256 blocks x 64 rows. Per step: 10 units of 32KB fp8
// through a per-wave 3-slot ring; sync within the step is ONLY the wave's own counted
// vmcnt (Ring regions are wave-private; At is read-only during phases). Just 2 barriers
// per step (around the h/x writeback). Af = 4 x ds_read_b128 (pair-packed weights).
__launch_bounds__(512, 2)
__global__ void k_lstm(const float* __restrict__ temporal, const uint8* __restrict__ wcq,
                       const float* __restrict__ biasg, const float* __restrict__ ah,
                       float* __restrict__ out) {
    __shared__ __attribute__((aligned(16))) char  Ring[3 * 32768];   // 98304 B
    __shared__ __attribute__((aligned(16))) char  At[64 * 328];      // 20992 B
    __shared__ __attribute__((aligned(16))) float Xf[64 * 56];       // 14336 B
    __shared__ __attribute__((aligned(16))) char  Xd[2048];          //  2048 B

    const int tid  = threadIdx.x;
    const int lane = tid & 63;
    const int w    = tid >> 6;          // 0..7
    const int l15  = lane & 15;
    const int l4q  = lane >> 4;         // 0..3
    const int row0 = blockIdx.x * 64;

    f32x4 bias[2][4];                   // [ht][q]
#pragma unroll
    for (int ht = 0; ht < 2; ++ht)
#pragma unroll
        for (int q = 0; q < 4; ++q)
            bias[ht][q] = *reinterpret_cast<const f32x4*>(biasg + q*256 + 32*w + 16*ht + 4*l4q);
    f32x4 ahv[2];
#pragma unroll
    for (int ht = 0; ht < 2; ++ht)
        ahv[ht] = *reinterpret_cast<const f32x4*>(ah + 32*w + 16*ht + 4*l4q);

    // x staging source offsets (bytes): wave w covers Xf bytes [2w*1024, 2w*1024+2048)
    long xo0, xo1;
    {
        int b0 = (2*w + 0)*1024 + lane*16;
        int b1 = (2*w + 1)*1024 + lane*16;
        xo0 = (long)(b0/224)*21504 + (b0 % 224);
        xo1 = (long)(b1/224)*21504 + (b1 % 224);
    }
    const char* xbase = (const char*)(temporal + (size_t)row0 * 5376);

    auto stage_w = [&](int slot, int uu) {
        const uint8* src = wcq + uu*32768 + w*4096 + lane*16;
        char* dst = Ring + slot*32768 + w*4096 + lane*16;
#pragma unroll
        for (int i = 0; i < 4; ++i)
            __builtin_amdgcn_global_load_lds(
                (const __attribute__((address_space(1))) uint32*)(src + i*1024),
                (__attribute__((address_space(3))) uint32*)(dst + i*1024), 16, 0, 0);
    };
    auto stage_x = [&](int tt) {
        if (w < 7) {
            const char* s0 = xbase + xo0 + (size_t)tt*224;
            const char* s1 = xbase + xo1 + (size_t)tt*224;
            float* d0 = Xf + (2*w)*256 + lane*4;
            float* d1 = Xf + (2*w+1)*256 + lane*4;
            __builtin_amdgcn_global_load_lds((const __attribute__((address_space(1))) uint32*)s0,
                                             (__attribute__((address_space(3))) uint32*)d0, 16, 0, 0);
            __builtin_amdgcn_global_load_lds((const __attribute__((address_space(1))) uint32*)s1,
                                             (__attribute__((address_space(3))) uint32*)d1, 16, 0, 0);
        } else {   // keep vmcnt uniform across waves
            const char* s0 = xbase + lane*16;
            __builtin_amdgcn_global_load_lds((const __attribute__((address_space(1))) uint32*)s0,
                                             (__attribute__((address_space(3))) uint32*)(Xd + lane*16), 16, 0, 0);
            __builtin_amdgcn_global_load_lds((const __attribute__((address_space(1))) uint32*)(s0 + 1024),
                                             (__attribute__((address_space(3))) uint32*)(Xd + 1024 + lane*16), 16, 0, 0);
        }
    };
    auto conv_x = [&]() {               // Xf (f32) -> At fp8, rows tid>>3, 8 cols each
        int xr = tid >> 3, xs = tid & 7;
        if (xs < 7) {
            const float* xf = Xf + xr*56 + xs*8;
            f32x4 a = *reinterpret_cast<const f32x4*>(xf);
            f32x4 b = *reinterpret_cast<const f32x4*>(xf + 4);
            uint32 lo = __builtin_amdgcn_cvt_pk_fp8_f32(a[0], a[1], 0, false);
            lo = __builtin_amdgcn_cvt_pk_fp8_f32(a[2], a[3], lo, true);
            uint32 hi = __builtin_amdgcn_cvt_pk_fp8_f32(b[0], b[1], 0, false);
            hi = __builtin_amdgcn_cvt_pk_fp8_f32(b[2], b[3], hi, true);
            uint32* p = reinterpret_cast<uint32*>(At + xr*328 + xs*8);
            p[0] = lo; p[1] = hi;
        } else {
            uint32* p = reinterpret_cast<uint32*>(At + xr*328 + 56);
            p[0] = 0u; p[1] = 0u;       // zero pad k=56..63
        }
    };

    // ---- prologue: x0 + units 0,1; zero At; convert x0 ----
    stage_x(0);
    stage_w(0, 0); stage_w(1, 1);
    for (int i = tid; i < 1312; i += 512)
        *reinterpret_cast<f32x4*>(At + i*16) = (f32x4){0.f,0.f,0.f,0.f};
    asm volatile("s_waitcnt vmcnt(0)" ::: "memory");
    __builtin_amdgcn_s_barrier();
    conv_x();
    asm volatile("s_waitcnt lgkmcnt(0)" ::: "memory");
    __builtin_amdgcn_s_barrier();

    f32x4 cst[4][2];                    // c state [rt][ht]
    f32x4 hv[4][2];                     // h(t), carried to epilogue
#pragma unroll
    for (int rt = 0; rt < 4; ++rt)
#pragma unroll
        for (int ht = 0; ht < 2; ++ht) cst[rt][ht] = (f32x4){0.f,0.f,0.f,0.f};

    int sl = 0;                         // ring slot of current unit (continuous mod 3)
#pragma unroll 1
    for (int t = 0; t < 96; ++t) {
        f32x4 acc[4][2][4];             // [rt][ht][q]
#pragma unroll
        for (int rt = 0; rt < 4; ++rt)
#pragma unroll
            for (int ht = 0; ht < 2; ++ht)
#pragma unroll
                for (int q = 0; q < 4; ++q)
                    acc[rt][ht][q] = bias[ht][q];

#pragma unroll 1
        for (int c = 0; c < 10; ++c) {
            // own-queue counted wait only; Ring regions are wave-private -> no barrier
            if (c == 1 || c == 2) asm volatile("s_waitcnt vmcnt(6)" ::: "memory");
            else                  asm volatile("s_waitcnt vmcnt(4)" ::: "memory");

            {   // 2-deep prefetch: unit c+2 -> slot (sl+2)%3
                int s2 = sl + 2; if (s2 >= 3) s2 -= 3;
                int u2 = c + 2;  if (u2 >= 10) u2 -= 10;
                stage_w(s2, u2);
            }
            if (c == 0) stage_x(t < 95 ? t + 1 : 95);

            const char* wb = Ring + sl*32768 + w*4096 + lane*16;
            ll_t Af[8];
#pragma unroll
            for (int j = 0; j < 4; ++j) {
                ll2 pr = *reinterpret_cast<const ll2*>(wb + j*1024);
                Af[2*j]   = pr.x;
                Af[2*j+1] = pr.y;
            }
            ll_t Bv[4];
#pragma unroll
            for (int rt = 0; rt < 4; ++rt)
                Bv[rt] = *reinterpret_cast<const ll_t*>(At + (rt*16 + l15)*328 + c*32 + l4q*8);
#pragma unroll
            for (int ht = 0; ht < 2; ++ht)
#pragma unroll
                for (int q = 0; q < 4; ++q) {
                    ll_t A = Af[ht*4 + q];
#pragma unroll
                    for (int rt = 0; rt < 4; ++rt)
                        acc[rt][ht][q] = __builtin_amdgcn_mfma_f32_16x16x32_fp8_fp8(
                            A, Bv[rt], acc[rt][ht][q], 0, 0, 0);
                }
            sl = sl + 1; if (sl >= 3) sl -= 3;
        }

        // ---- gates -> c, h (thread-local; e = adjacent hidden dims, one batch row) ----
#pragma unroll
        for (int rt = 0; rt < 4; ++rt)
#pragma unroll
            for (int ht = 0; ht < 2; ++ht)
#pragma unroll
                for (int e = 0; e < 4; ++e) {
                    float ig = sigmoidf_fast(acc[rt][ht][0][e]);
                    float fg = sigmoidf_fast(acc[rt][ht][1][e]);
                    float gt = tanhf_fast  (acc[rt][ht][2][e]);
                    float og = sigmoidf_fast(acc[rt][ht][3][e]);
                    float cn = fg * cst[rt][ht][e] + ig * gt;
                    cst[rt][ht][e] = cn;
                    hv[rt][ht][e] = og * tanhf_fast(cn);
                }

        if (t < 95) {
            __builtin_amdgcn_s_barrier();        // A: all At reads of this step done
#pragma unroll
            for (int rt = 0; rt < 4; ++rt)
#pragma unroll
                for (int ht = 0; ht < 2; ++ht) {
                    uint32 pk = __builtin_amdgcn_cvt_pk_fp8_f32(hv[rt][ht][0], hv[rt][ht][1], 0, false);
                    pk = __builtin_amdgcn_cvt_pk_fp8_f32(hv[rt][ht][2], hv[rt][ht][3], pk, true);
                    *reinterpret_cast<uint32*>(
                        At + (rt*16 + l15)*328 + 64 + 32*w + 16*ht + 4*l4q) = pk;
                }
            conv_x();
            asm volatile("s_waitcnt lgkmcnt(0)" ::: "memory");
            __builtin_amdgcn_s_barrier();        // B: writes visible
        }
    }

    // ---- epilogue: out[row] += ah . h_T[row] ----
    {
        float part[4];
#pragma unroll
        for (int rt = 0; rt < 4; ++rt) {
            float s = 0.f;
#pragma unroll
            for (int ht = 0; ht < 2; ++ht)
#pragma unroll
                for (int e = 0; e < 4; ++e)
                    s += ahv[ht][e] * hv[rt][ht][e];
            s += __shfl_xor(s, 16);
            s += __shfl_xor(s, 32);
            part[rt] = s;
        }
        __builtin_amdgcn_s_barrier();
        float* sc = reinterpret_cast<float*>(Ring);
        if (l4q == 0)
#pragma unroll
            for (int rt = 0; rt < 4; ++rt)
                sc[w*64 + rt*16 + l15] = part[rt];
        asm volatile("s_waitcnt lgkmcnt(0)" ::: "memory");
        __builtin_amdgcn_s_barrier();
        if (tid < 64) {
            float s = 0.f;
#pragma unroll
            for (int wv = 0; wv < 8; ++wv) s += sc[wv*64 + tid];
            out[row0 + tid] += s;
        }
    }
}

// ---------------- launch ----------------
extern "C" void kernel_launch(void* const* d_in, const int* in_sizes, int n_in,
                              void* d_out, int out_size, void* d_ws, size_t ws_size,
                              hipStream_t stream) {
    const float* spatial  = (const float*)d_in[0];
    const float* temporal = (const float*)d_in[1];
    const float* sl_w = (const float*)d_in[2];  const float* sl_b = (const float*)d_in[3];
    const float* st_w = (const float*)d_in[4];  const float* st_b = (const float*)d_in[5];
    const float* seg_w = (const float*)d_in[6]; const float* seg_b = (const float*)d_in[7];
    const float* l1_w = (const float*)d_in[8];  const float* l1_b = (const float*)d_in[9];
    const float* l2_w = (const float*)d_in[10]; const float* l2_b = (const float*)d_in[11];
    const float* w_ih = (const float*)d_in[12]; const float* b_ih = (const float*)d_in[13];
    const float* w_hh = (const float*)d_in[14]; const float* b_hh = (const float*)d_in[15];
    const float* l4_w = (const float*)d_in[16]; const float* l4_b = (const float*)d_in[17];
    const float* l5_w = (const float*)d_in[18]; const float* l5_b = (const float*)d_in[19];
    const float* l6_w = (const float*)d_in[20]; const float* l6_b = (const float*)d_in[21];
    const float* l7_w = (const float*)d_in[22]; const float* l7_b = (const float*)d_in[23];

    char* ws = (char*)d_ws;
    float*  wsp   = (float*)(ws + WS_WSP);
    float*  ah    = (float*)(ws + WS_AH);
    float*  u527  = (float*)(ws + WS_U527);
    float*  biasT = (float*)(ws + WS_BIAS);
    float*  biasg = (float*)(ws + WS_BIASG);
    uint8*  wcq   = (uint8*)(ws + WS_WC);

    float* out = (float*)d_out;

    hipLaunchKernelGGL(k_head, dim3(1), dim3(512), 0, stream,
                       sl_w, sl_b, st_w, st_b, seg_b, l1_w, l1_b, l2_w, l2_b,
                       l4_w, l4_b, l5_w, l5_b, l6_w, l6_b, l7_w, l7_b,
                       wsp, ah, u527, biasT);
    hipLaunchKernelGGL(k_seg, dim3(5), dim3(256), 0, stream, seg_w, u527, wsp);
    hipLaunchKernelGGL(k_wcq, dim3(1280), dim3(256), 0, stream,
                       w_ih, b_ih, w_hh, b_hh, wcq, biasg);
    hipLaunchKernelGGL(k_spatial, dim3(16384/4), dim3(256), 0, stream,
                       spatial, wsp, biasT, out);
    hipLaunchKernelGGL(k_lstm, dim3(256), dim3(512), 0, stream,
                       temporal, wcq, biasg, ah, out);
}

// Round 13
// 1191.631 us; speedup vs baseline: 4.0602x; 1.4263x over previous
//
#include <hip/hip_runtime.h>
#include <hip/hip_bf16.h>
#include <math.h>

typedef __bf16 bf16_t;
typedef float  f32x4  __attribute__((ext_vector_type(4)));
typedef unsigned int uint32;
typedef unsigned char uint8;
typedef long long ll_t;
typedef long long ll2 __attribute__((ext_vector_type(2)));

// ---------------- workspace layout (bytes) ----------------
#define WS_WSP    0        // 1297 f32
#define WS_AH     5248     // 256 f32
#define WS_U527   6272     // 527 f32
#define WS_BIAS   8384     // 1 f32
#define WS_BIASG  8448     // 1024 f32
#define WS_WC     12544    // 327680 B fp8 weights: 10 units x 32KB

// Hardware-rate gate math: v_exp_f32 (exp2) + v_rcp_f32, ~1ulp, exact saturation.
__device__ __forceinline__ float sigmoid_hw(float x) {
    float e = __builtin_amdgcn_exp2f(-1.44269504f * x);
    return __builtin_amdgcn_rcpf(1.f + e);
}
__device__ __forceinline__ float tanh_hw(float x) {
    float e = __builtin_amdgcn_exp2f(2.88539008f * x);
    return 1.f - 2.f * __builtin_amdgcn_rcpf(1.f + e);
}

// ---------------- head/spatial weight composition (tiny) ----------------
__global__ void k_head(const float* __restrict__ sl_w, const float* __restrict__ sl_b,
                       const float* __restrict__ st_w, const float* __restrict__ st_b,
                       const float* __restrict__ seg_b,
                       const float* __restrict__ l1_w, const float* __restrict__ l1_b,
                       const float* __restrict__ l2_w, const float* __restrict__ l2_b,
                       const float* __restrict__ l4_w, const float* __restrict__ l4_b,
                       const float* __restrict__ l5_w, const float* __restrict__ l5_b,
                       const float* __restrict__ l6_w, const float* __restrict__ l6_b,
                       const float* __restrict__ l7_w, const float* __restrict__ l7_b,
                       float* __restrict__ wsp, float* __restrict__ ah,
                       float* __restrict__ u527_out, float* __restrict__ bias_out) {
    __shared__ float v2[128], v3[256], aa[384], u256[256], u527[527];
    __shared__ float red[8];
    const int t = threadIdx.x;   // 512 threads

    if (t < 128) { float s = 0.f; for (int i = 0; i < 128; ++i) s += l7_w[i] * l6_w[i*128 + t]; v2[t] = s; }
    __syncthreads();
    if (t < 256) { float s = 0.f; for (int i = 0; i < 128; ++i) s += v2[i] * l5_w[i*256 + t]; v3[t] = s; }
    __syncthreads();
    if (t < 384) { float s = 0.f; for (int i = 0; i < 256; ++i) s += v3[i] * l4_w[i*384 + t]; aa[t] = s; }
    __syncthreads();
    if (t < 256) { float s = 0.f; for (int i = 0; i < 128; ++i) s += aa[i] * l2_w[i*256 + t]; u256[t] = s; }
    if (t < 256) ah[t] = aa[128 + t];
    __syncthreads();
    for (int j = t; j < 527; j += 512) {
        float s = 0.f;
        for (int i = 0; i < 256; ++i) s += u256[i] * l1_w[i*527 + j];
        u527[j] = s; u527_out[j] = s;
    }
    __syncthreads();
    if (t < 4)              { float s = 0.f; for (int i = 0; i < 2; ++i) s += u527[i]     * sl_w[i*4  + t];      wsp[t] = s; }
    else if (t < 16)        { int c = t - 4;  float s = 0.f; for (int i = 0; i < 8; ++i) s += u527[2+i] * st_w[i*12 + c]; wsp[t] = s; }
    else if (t < 21)        { wsp[1292 + (t - 16)] = u527[522 + (t - 16)]; }
    float p = 0.f;
    if (t < 128) p += l7_w[t] * l6_b[t] + v2[t] * l5_b[t] + aa[t] * l2_b[t];
    if (t < 256) p += v3[t] * l4_b[t] + u256[t] * l1_b[t];
    if (t < 2)   p += u527[t] * sl_b[t];
    if (t < 8)   p += u527[2 + t] * st_b[t];
    p += u527[10 + t] * seg_b[t];
    p += __shfl_xor(p, 1);  p += __shfl_xor(p, 2);  p += __shfl_xor(p, 4);
    p += __shfl_xor(p, 8);  p += __shfl_xor(p, 16); p += __shfl_xor(p, 32);
    if ((t & 63) == 0) red[t >> 6] = p;
    __syncthreads();
    if (t == 0) {
        float s = l7_b[0];
        for (int i = 0; i < 8; ++i) s += red[i];
        *bias_out = s;
    }
}

__global__ void k_seg(const float* __restrict__ seg_w, const float* __restrict__ u527,
                      float* __restrict__ wsp) {
    int j = blockIdx.x * 256 + threadIdx.x;
    if (j >= 1276) return;
    float s = 0.f;
    for (int i = 0; i < 512; ++i) s += u527[10 + i] * seg_w[i*1276 + j];
    wsp[16 + j] = s;
}

// fp8 weights, W as the MFMA A-operand, PAIR-PACKED for ds_read_b128.
// Unit kk = 32KB at kk*32768; wave region w*4096; issue j (0..3) at j*1024;
// lane block lane*16 (16 B): bytes 0..7 = frag f=2j, bytes 8..15 = frag f=2j+1.
// Frag f = ht*4+q: n = q*256 + 32w + 16ht + (lane&15); k = kk*32 + (lane>>4)*8 + e.
__global__ void k_wcq(const float* __restrict__ w_ih, const float* __restrict__ b_ih,
                      const float* __restrict__ w_hh, const float* __restrict__ b_hh,
                      uint8* __restrict__ wcq, float* __restrict__ biasg) {
    int idx = blockIdx.x * 256 + threadIdx.x;
    if (idx < 1024) biasg[idx] = b_ih[idx] + b_hh[idx];
    if (idx < 327680) {
        int kk = idx >> 15;
        int r  = idx & 32767;
        int w  = r >> 12;
        int r2 = r & 4095;
        int j  = r2 >> 10;
        int r3 = r2 & 1023;
        int lane = r3 >> 4;
        int b  = r3 & 15;
        int f  = 2*j + (b >> 3);
        int e  = b & 7;
        int ht = f >> 2, q = f & 3;
        int n = q*256 + 32*w + 16*ht + (lane & 15);
        int k = kk*32 + ((lane >> 4) << 3) + e;
        float v = 0.f;
        if (k < 56)       v = w_ih[n*56 + k];
        else if (k >= 64) v = w_hh[n*256 + (k - 64)];
        uint32 pk = __builtin_amdgcn_cvt_pk_fp8_f32(v, 0.f, 0, false);
        wcq[idx] = (uint8)(pk & 0xff);
    }
}

__global__ void k_spatial(const float* __restrict__ sp, const float* __restrict__ wsp,
                          const float* __restrict__ bias, float* __restrict__ out) {
    int row  = blockIdx.x * 4 + (threadIdx.x >> 6);
    int lane = threadIdx.x & 63;
    const float* rp = sp + (size_t)row * 1297;
    float s = 0.f;
    for (int k = lane; k < 1297; k += 64) s += rp[k] * wsp[k];
    s += __shfl_xor(s, 1);  s += __shfl_xor(s, 2);  s += __shfl_xor(s, 4);
    s += __shfl_xor(s, 8);  s += __shfl_xor(s, 16); s += __shfl_xor(s, 32);
    if (lane == 0) out[row] = s + bias[0];
}

// ---------------- LSTM v12: hw-rate gates + issue-before-wait fp8 stream ----------------
// 512 thr / 8 waves / 1 block/CU, 256 blocks x 64 rows. 10 fp8 units/step through a
// per-wave 3-slot ring; DMA issued BEFORE the counted wait (deeper effective pipeline);
// only 2 barriers/step. Gates via v_exp_f32/v_rcp_f32 (no IEEE div / libm exp).
__launch_bounds__(512, 2)
__global__ void k_lstm(const float* __restrict__ temporal, const uint8* __restrict__ wcq,
                       const float* __restrict__ biasg, const float* __restrict__ ah,
                       float* __restrict__ out) {
    __shared__ __attribute__((aligned(16))) char  Ring[3 * 32768];   // 98304 B
    __shared__ __attribute__((aligned(16))) char  At[64 * 328];      // 20992 B
    __shared__ __attribute__((aligned(16))) float Xf[64 * 56];       // 14336 B
    __shared__ __attribute__((aligned(16))) char  Xd[2048];          //  2048 B

    const int tid  = threadIdx.x;
    const int lane = tid & 63;
    const int w    = tid >> 6;          // 0..7
    const int l15  = lane & 15;
    const int l4q  = lane >> 4;         // 0..3
    const int row0 = blockIdx.x * 64;

    f32x4 bias[2][4];                   // [ht][q]
#pragma unroll
    for (int ht = 0; ht < 2; ++ht)
#pragma unroll
        for (int q = 0; q < 4; ++q)
            bias[ht][q] = *reinterpret_cast<const f32x4*>(biasg + q*256 + 32*w + 16*ht + 4*l4q);
    f32x4 ahv[2];
#pragma unroll
    for (int ht = 0; ht < 2; ++ht)
        ahv[ht] = *reinterpret_cast<const f32x4*>(ah + 32*w + 16*ht + 4*l4q);

    // x staging source offsets (bytes): wave w covers Xf bytes [2w*1024, 2w*1024+2048)
    long xo0, xo1;
    {
        int b0 = (2*w + 0)*1024 + lane*16;
        int b1 = (2*w + 1)*1024 + lane*16;
        xo0 = (long)(b0/224)*21504 + (b0 % 224);
        xo1 = (long)(b1/224)*21504 + (b1 % 224);
    }
    const char* xbase = (const char*)(temporal + (size_t)row0 * 5376);

    auto stage_w = [&](int slot, int uu) {
        const uint8* src = wcq + uu*32768 + w*4096 + lane*16;
        char* dst = Ring + slot*32768 + w*4096 + lane*16;
#pragma unroll
        for (int i = 0; i < 4; ++i)
            __builtin_amdgcn_global_load_lds(
                (const __attribute__((address_space(1))) uint32*)(src + i*1024),
                (__attribute__((address_space(3))) uint32*)(dst + i*1024), 16, 0, 0);
    };
    auto stage_x = [&](int tt) {
        if (w < 7) {
            const char* s0 = xbase + xo0 + (size_t)tt*224;
            const char* s1 = xbase + xo1 + (size_t)tt*224;
            float* d0 = Xf + (2*w)*256 + lane*4;
            float* d1 = Xf + (2*w+1)*256 + lane*4;
            __builtin_amdgcn_global_load_lds((const __attribute__((address_space(1))) uint32*)s0,
                                             (__attribute__((address_space(3))) uint32*)d0, 16, 0, 0);
            __builtin_amdgcn_global_load_lds((const __attribute__((address_space(1))) uint32*)s1,
                                             (__attribute__((address_space(3))) uint32*)d1, 16, 0, 0);
        } else {   // keep vmcnt uniform across waves
            const char* s0 = xbase + lane*16;
            __builtin_amdgcn_global_load_lds((const __attribute__((address_space(1))) uint32*)s0,
                                             (__attribute__((address_space(3))) uint32*)(Xd + lane*16), 16, 0, 0);
            __builtin_amdgcn_global_load_lds((const __attribute__((address_space(1))) uint32*)(s0 + 1024),
                                             (__attribute__((address_space(3))) uint32*)(Xd + 1024 + lane*16), 16, 0, 0);
        }
    };
    auto conv_x = [&]() {               // Xf (f32) -> At fp8, rows tid>>3, 8 cols each
        int xr = tid >> 3, xs = tid & 7;
        if (xs < 7) {
            const float* xf = Xf + xr*56 + xs*8;
            f32x4 a = *reinterpret_cast<const f32x4*>(xf);
            f32x4 b = *reinterpret_cast<const f32x4*>(xf + 4);
            uint32 lo = __builtin_amdgcn_cvt_pk_fp8_f32(a[0], a[1], 0, false);
            lo = __builtin_amdgcn_cvt_pk_fp8_f32(a[2], a[3], lo, true);
            uint32 hi = __builtin_amdgcn_cvt_pk_fp8_f32(b[0], b[1], 0, false);
            hi = __builtin_amdgcn_cvt_pk_fp8_f32(b[2], b[3], hi, true);
            uint32* p = reinterpret_cast<uint32*>(At + xr*328 + xs*8);
            p[0] = lo; p[1] = hi;
        } else {
            uint32* p = reinterpret_cast<uint32*>(At + xr*328 + 56);
            p[0] = 0u; p[1] = 0u;       // zero pad k=56..63
        }
    };

    // ---- prologue: x0 + units 0,1; zero At; convert x0 ----
    stage_x(0);
    stage_w(0, 0); stage_w(1, 1);
    for (int i = tid; i < 1312; i += 512)
        *reinterpret_cast<f32x4*>(At + i*16) = (f32x4){0.f,0.f,0.f,0.f};
    asm volatile("s_waitcnt vmcnt(0)" ::: "memory");
    __builtin_amdgcn_s_barrier();
    conv_x();
    asm volatile("s_waitcnt lgkmcnt(0)" ::: "memory");
    __builtin_amdgcn_s_barrier();

    f32x4 cst[4][2];                    // c state [rt][ht]
    f32x4 hv[4][2];                     // h(t), carried to epilogue
#pragma unroll
    for (int rt = 0; rt < 4; ++rt)
#pragma unroll
        for (int ht = 0; ht < 2; ++ht) cst[rt][ht] = (f32x4){0.f,0.f,0.f,0.f};

    int sl = 0;                         // ring slot of current unit (continuous mod 3)
#pragma unroll 1
    for (int t = 0; t < 96; ++t) {
        f32x4 acc[4][2][4];             // [rt][ht][q]
#pragma unroll
        for (int rt = 0; rt < 4; ++rt)
#pragma unroll
            for (int ht = 0; ht < 2; ++ht)
#pragma unroll
                for (int q = 0; q < 4; ++q)
                    acc[rt][ht][q] = bias[ht][q];

#pragma unroll 1
        for (int c = 0; c < 10; ++c) {
            // issue-before-wait: DMA for unit c+2 (and x at c==0) enters the queue first
            {
                int s2 = sl + 2; if (s2 >= 3) s2 -= 3;
                int u2 = c + 2;  if (u2 >= 10) u2 -= 10;
                stage_w(s2, u2);
            }
            if (c == 0) stage_x(t < 95 ? t + 1 : 95);
            // own-queue counted wait: unit c landed. c<3: +2 for the x loads in queue.
            if (c < 3) asm volatile("s_waitcnt vmcnt(10)" ::: "memory");
            else       asm volatile("s_waitcnt vmcnt(8)"  ::: "memory");

            const char* wb = Ring + sl*32768 + w*4096 + lane*16;
            ll_t Af[8];
#pragma unroll
            for (int j = 0; j < 4; ++j) {
                ll2 pr = *reinterpret_cast<const ll2*>(wb + j*1024);
                Af[2*j]   = pr.x;
                Af[2*j+1] = pr.y;
            }
            ll_t Bv[4];
#pragma unroll
            for (int rt = 0; rt < 4; ++rt)
                Bv[rt] = *reinterpret_cast<const ll_t*>(At + (rt*16 + l15)*328 + c*32 + l4q*8);
#pragma unroll
            for (int ht = 0; ht < 2; ++ht)
#pragma unroll
                for (int q = 0; q < 4; ++q) {
                    ll_t A = Af[ht*4 + q];
#pragma unroll
                    for (int rt = 0; rt < 4; ++rt)
                        acc[rt][ht][q] = __builtin_amdgcn_mfma_f32_16x16x32_fp8_fp8(
                            A, Bv[rt], acc[rt][ht][q], 0, 0, 0);
                }
            sl = sl + 1; if (sl >= 3) sl -= 3;
        }

        // ---- gates -> c, h (hw-rate transcendentals; thread-local) ----
#pragma unroll
        for (int rt = 0; rt < 4; ++rt)
#pragma unroll
            for (int ht = 0; ht < 2; ++ht)
#pragma unroll
                for (int e = 0; e < 4; ++e) {
                    float ig = sigmoid_hw(acc[rt][ht][0][e]);
                    float fg = sigmoid_hw(acc[rt][ht][1][e]);
                    float gt = tanh_hw  (acc[rt][ht][2][e]);
                    float og = sigmoid_hw(acc[rt][ht][3][e]);
                    float cn = fg * cst[rt][ht][e] + ig * gt;
                    cst[rt][ht][e] = cn;
                    hv[rt][ht][e] = og * tanh_hw(cn);
                }

        if (t < 95) {
            __builtin_amdgcn_s_barrier();        // A: all At reads of this step done
#pragma unroll
            for (int rt = 0; rt < 4; ++rt)
#pragma unroll
                for (int ht = 0; ht < 2; ++ht) {
                    uint32 pk = __builtin_amdgcn_cvt_pk_fp8_f32(hv[rt][ht][0], hv[rt][ht][1], 0, false);
                    pk = __builtin_amdgcn_cvt_pk_fp8_f32(hv[rt][ht][2], hv[rt][ht][3], pk, true);
                    *reinterpret_cast<uint32*>(
                        At + (rt*16 + l15)*328 + 64 + 32*w + 16*ht + 4*l4q) = pk;
                }
            conv_x();
            asm volatile("s_waitcnt lgkmcnt(0)" ::: "memory");
            __builtin_amdgcn_s_barrier();        // B: writes visible
        }
    }

    // ---- epilogue: out[row] += ah . h_T[row] ----
    {
        float part[4];
#pragma unroll
        for (int rt = 0; rt < 4; ++rt) {
            float s = 0.f;
#pragma unroll
            for (int ht = 0; ht < 2; ++ht)
#pragma unroll
                for (int e = 0; e < 4; ++e)
                    s += ahv[ht][e] * hv[rt][ht][e];
            s += __shfl_xor(s, 16);
            s += __shfl_xor(s, 32);
            part[rt] = s;
        }
        __builtin_amdgcn_s_barrier();
        float* sc = reinterpret_cast<float*>(Ring);
        if (l4q == 0)
#pragma unroll
            for (int rt = 0; rt < 4; ++rt)
                sc[w*64 + rt*16 + l15] = part[rt];
        asm volatile("s_waitcnt lgkmcnt(0)" ::: "memory");
        __builtin_amdgcn_s_barrier();
        if (tid < 64) {
            float s = 0.f;
#pragma unroll
            for (int wv = 0; wv < 8; ++wv) s += sc[wv*64 + tid];
            out[row0 + tid] += s;
        }
    }
}

// ---------------- launch ----------------
extern "C" void kernel_launch(void* const* d_in, const int* in_sizes, int n_in,
                              void* d_out, int out_size, void* d_ws, size_t ws_size,
                              hipStream_t stream) {
    const float* spatial  = (const float*)d_in[0];
    const float* temporal = (const float*)d_in[1];
    const float* sl_w = (const float*)d_in[2];  const float* sl_b = (const float*)d_in[3];
    const float* st_w = (const float*)d_in[4];  const float* st_b = (const float*)d_in[5];
    const float* seg_w = (const float*)d_in[6]; const float* seg_b = (const float*)d_in[7];
    const float* l1_w = (const float*)d_in[8];  const float* l1_b = (const float*)d_in[9];
    const float* l2_w = (const float*)d_in[10]; const float* l2_b = (const float*)d_in[11];
    const float* w_ih = (const float*)d_in[12]; const float* b_ih = (const float*)d_in[13];
    const float* w_hh = (const float*)d_in[14]; const float* b_hh = (const float*)d_in[15];
    const float* l4_w = (const float*)d_in[16]; const float* l4_b = (const float*)d_in[17];
    const float* l5_w = (const float*)d_in[18]; const float* l5_b = (const float*)d_in[19];
    const float* l6_w = (const float*)d_in[20]; const float* l6_b = (const float*)d_in[21];
    const float* l7_w = (const float*)d_in[22]; const float* l7_b = (const float*)d_in[23];

    char* ws = (char*)d_ws;
    float*  wsp   = (float*)(ws + WS_WSP);
    float*  ah    = (float*)(ws + WS_AH);
    float*  u527  = (float*)(ws + WS_U527);
    float*  biasT = (float*)(ws + WS_BIAS);
    float*  biasg = (float*)(ws + WS_BIASG);
    uint8*  wcq   = (uint8*)(ws + WS_WC);

    float* out = (float*)d_out;

    hipLaunchKernelGGL(k_head, dim3(1), dim3(512), 0, stream,
                       sl_w, sl_b, st_w, st_b, seg_b, l1_w, l1_b, l2_w, l2_b,
                       l4_w, l4_b, l5_w, l5_b, l6_w, l6_b, l7_w, l7_b,
                       wsp, ah, u527, biasT);
    hipLaunchKernelGGL(k_seg, dim3(5), dim3(256), 0, stream, seg_w, u527, wsp);
    hipLaunchKernelGGL(k_wcq, dim3(1280), dim3(256), 0, stream,
                       w_ih, b_ih, w_hh, b_hh, wcq, biasg);
    hipLaunchKernelGGL(k_spatial, dim3(16384/4), dim3(256), 0, stream,
                       spatial, wsp, biasT, out);
    hipLaunchKernelGGL(k_lstm, dim3(256), dim3(512), 0, stream,
                       temporal, wcq, biasg, ah, out);
}

// Round 14
// 1155.367 us; speedup vs baseline: 4.1877x; 1.0314x over previous
//
#include <hip/hip_runtime.h>
#include <hip/hip_bf16.h>
#include <math.h>

typedef __bf16 bf16_t;
typedef float  f32x4  __attribute__((ext_vector_type(4)));
typedef unsigned int uint32;
typedef unsigned char uint8;
typedef long long ll_t;
typedef long long ll2 __attribute__((ext_vector_type(2)));

// ---------------- workspace layout (bytes) ----------------
#define WS_WSP    0        // 1297 f32
#define WS_AH     5248     // 256 f32
#define WS_U527   6272     // 527 f32
#define WS_BIAS   8384     // 1 f32
#define WS_BIASG  8448     // 1024 f32
#define WS_WC     12544    // 327680 B fp8 weights: 10 units x 32KB

// Hardware-rate gate math: v_exp_f32 (exp2) + v_rcp_f32, ~1ulp, exact saturation.
__device__ __forceinline__ float sigmoid_hw(float x) {
    float e = __builtin_amdgcn_exp2f(-1.44269504f * x);
    return __builtin_amdgcn_rcpf(1.f + e);
}
__device__ __forceinline__ float tanh_hw(float x) {
    float e = __builtin_amdgcn_exp2f(2.88539008f * x);
    return 1.f - 2.f * __builtin_amdgcn_rcpf(1.f + e);
}

// ---------------- head/spatial weight composition (tiny) ----------------
__global__ void k_head(const float* __restrict__ sl_w, const float* __restrict__ sl_b,
                       const float* __restrict__ st_w, const float* __restrict__ st_b,
                       const float* __restrict__ seg_b,
                       const float* __restrict__ l1_w, const float* __restrict__ l1_b,
                       const float* __restrict__ l2_w, const float* __restrict__ l2_b,
                       const float* __restrict__ l4_w, const float* __restrict__ l4_b,
                       const float* __restrict__ l5_w, const float* __restrict__ l5_b,
                       const float* __restrict__ l6_w, const float* __restrict__ l6_b,
                       const float* __restrict__ l7_w, const float* __restrict__ l7_b,
                       float* __restrict__ wsp, float* __restrict__ ah,
                       float* __restrict__ u527_out, float* __restrict__ bias_out) {
    __shared__ float v2[128], v3[256], aa[384], u256[256], u527[527];
    __shared__ float red[8];
    const int t = threadIdx.x;   // 512 threads

    if (t < 128) { float s = 0.f; for (int i = 0; i < 128; ++i) s += l7_w[i] * l6_w[i*128 + t]; v2[t] = s; }
    __syncthreads();
    if (t < 256) { float s = 0.f; for (int i = 0; i < 128; ++i) s += v2[i] * l5_w[i*256 + t]; v3[t] = s; }
    __syncthreads();
    if (t < 384) { float s = 0.f; for (int i = 0; i < 256; ++i) s += v3[i] * l4_w[i*384 + t]; aa[t] = s; }
    __syncthreads();
    if (t < 256) { float s = 0.f; for (int i = 0; i < 128; ++i) s += aa[i] * l2_w[i*256 + t]; u256[t] = s; }
    if (t < 256) ah[t] = aa[128 + t];
    __syncthreads();
    for (int j = t; j < 527; j += 512) {
        float s = 0.f;
        for (int i = 0; i < 256; ++i) s += u256[i] * l1_w[i*527 + j];
        u527[j] = s; u527_out[j] = s;
    }
    __syncthreads();
    if (t < 4)              { float s = 0.f; for (int i = 0; i < 2; ++i) s += u527[i]     * sl_w[i*4  + t];      wsp[t] = s; }
    else if (t < 16)        { int c = t - 4;  float s = 0.f; for (int i = 0; i < 8; ++i) s += u527[2+i] * st_w[i*12 + c]; wsp[t] = s; }
    else if (t < 21)        { wsp[1292 + (t - 16)] = u527[522 + (t - 16)]; }
    float p = 0.f;
    if (t < 128) p += l7_w[t] * l6_b[t] + v2[t] * l5_b[t] + aa[t] * l2_b[t];
    if (t < 256) p += v3[t] * l4_b[t] + u256[t] * l1_b[t];
    if (t < 2)   p += u527[t] * sl_b[t];
    if (t < 8)   p += u527[2 + t] * st_b[t];
    p += u527[10 + t] * seg_b[t];
    p += __shfl_xor(p, 1);  p += __shfl_xor(p, 2);  p += __shfl_xor(p, 4);
    p += __shfl_xor(p, 8);  p += __shfl_xor(p, 16); p += __shfl_xor(p, 32);
    if ((t & 63) == 0) red[t >> 6] = p;
    __syncthreads();
    if (t == 0) {
        float s = l7_b[0];
        for (int i = 0; i < 8; ++i) s += red[i];
        *bias_out = s;
    }
}

__global__ void k_seg(const float* __restrict__ seg_w, const float* __restrict__ u527,
                      float* __restrict__ wsp) {
    int j = blockIdx.x * 256 + threadIdx.x;
    if (j >= 1276) return;
    float s = 0.f;
    for (int i = 0; i < 512; ++i) s += u527[10 + i] * seg_w[i*1276 + j];
    wsp[16 + j] = s;
}

// fp8 weights, W as the MFMA A-operand, PAIR-PACKED for ds_read_b128.
// Unit kk = 32KB at kk*32768; wave region w*4096; issue j (0..3) at j*1024;
// lane block lane*16 (16 B): bytes 0..7 = frag f=2j, bytes 8..15 = frag f=2j+1.
// Frag f = ht*4+q: n = q*256 + 32w + 16ht + (lane&15); k = kk*32 + (lane>>4)*8 + e.
__global__ void k_wcq(const float* __restrict__ w_ih, const float* __restrict__ b_ih,
                      const float* __restrict__ w_hh, const float* __restrict__ b_hh,
                      uint8* __restrict__ wcq, float* __restrict__ biasg) {
    int idx = blockIdx.x * 256 + threadIdx.x;
    if (idx < 1024) biasg[idx] = b_ih[idx] + b_hh[idx];
    if (idx < 327680) {
        int kk = idx >> 15;
        int r  = idx & 32767;
        int w  = r >> 12;
        int r2 = r & 4095;
        int j  = r2 >> 10;
        int r3 = r2 & 1023;
        int lane = r3 >> 4;
        int b  = r3 & 15;
        int f  = 2*j + (b >> 3);
        int e  = b & 7;
        int ht = f >> 2, q = f & 3;
        int n = q*256 + 32*w + 16*ht + (lane & 15);
        int k = kk*32 + ((lane >> 4) << 3) + e;
        float v = 0.f;
        if (k < 56)       v = w_ih[n*56 + k];
        else if (k >= 64) v = w_hh[n*256 + (k - 64)];
        uint32 pk = __builtin_amdgcn_cvt_pk_fp8_f32(v, 0.f, 0, false);
        wcq[idx] = (uint8)(pk & 0xff);
    }
}

__global__ void k_spatial(const float* __restrict__ sp, const float* __restrict__ wsp,
                          const float* __restrict__ bias, float* __restrict__ out) {
    int row  = blockIdx.x * 4 + (threadIdx.x >> 6);
    int lane = threadIdx.x & 63;
    const float* rp = sp + (size_t)row * 1297;
    float s = 0.f;
    for (int k = lane; k < 1297; k += 64) s += rp[k] * wsp[k];
    s += __shfl_xor(s, 1);  s += __shfl_xor(s, 2);  s += __shfl_xor(s, 4);
    s += __shfl_xor(s, 8);  s += __shfl_xor(s, 16); s += __shfl_xor(s, 32);
    if (lane == 0) out[row] = s + bias[0];
}

// ---------------- LSTM v13: double-buffered activations, 1 barrier/step ----------------
// 512 thr / 8 waves / 1 block/CU, 256 blocks x 64 rows. 10 fp8 units/step through a
// per-wave 3-slot ring with issue-after-consume depth-3 prefetch (96KB in flight across
// the gate window). Activations double-buffered (Xa[2], Ah[2], granule-XOR swizzle) ->
// exactly ONE lgkmcnt+barrier per step. Gates via v_exp_f32/v_rcp_f32.
__launch_bounds__(512, 2)
__global__ void k_lstm(const float* __restrict__ temporal, const uint8* __restrict__ wcq,
                       const float* __restrict__ biasg, const float* __restrict__ ah,
                       float* __restrict__ out) {
    __shared__ __attribute__((aligned(16))) char  Ring[3 * 32768];   // 98304 B
    __shared__ __attribute__((aligned(16))) char  Ah[2 * 16384];     // 32768 B fp8 h
    __shared__ __attribute__((aligned(16))) char  Xa[2 * 4096];      //  8192 B fp8 x
    __shared__ __attribute__((aligned(16))) float Xf[64 * 56];       // 14336 B f32 x stage
    __shared__ __attribute__((aligned(16))) char  Xd[2048];          //  2048 B dummy

    const int tid  = threadIdx.x;
    const int lane = tid & 63;
    const int w    = tid >> 6;          // 0..7
    const int l15  = lane & 15;
    const int l4q  = lane >> 4;         // 0..3
    const int row0 = blockIdx.x * 64;

    f32x4 bias[2][4];                   // [ht][q]
#pragma unroll
    for (int ht = 0; ht < 2; ++ht)
#pragma unroll
        for (int q = 0; q < 4; ++q)
            bias[ht][q] = *reinterpret_cast<const f32x4*>(biasg + q*256 + 32*w + 16*ht + 4*l4q);
    f32x4 ahv[2];
#pragma unroll
    for (int ht = 0; ht < 2; ++ht)
        ahv[ht] = *reinterpret_cast<const f32x4*>(ah + 32*w + 16*ht + 4*l4q);

    // per-rt B-read invariants (row = rt*16 + l15)
    int hbase[4], hswz[4], xbase_o[4];
#pragma unroll
    for (int rt = 0; rt < 4; ++rt) {
        int row = rt*16 + l15;
        hswz[rt]   = row & 7;
        hbase[rt]  = row*256 + (l4q << 3);
        xbase_o[rt]= row*64;
    }

    // x staging source offsets (bytes): wave w covers Xf bytes [2w*1024, 2w*1024+2048)
    long xo0, xo1;
    {
        int b0 = (2*w + 0)*1024 + lane*16;
        int b1 = (2*w + 1)*1024 + lane*16;
        xo0 = (long)(b0/224)*21504 + (b0 % 224);
        xo1 = (long)(b1/224)*21504 + (b1 % 224);
    }
    const char* xsrc = (const char*)(temporal + (size_t)row0 * 5376);

    auto stage_w = [&](int slot, int uu) {
        const uint8* src = wcq + uu*32768 + w*4096 + lane*16;
        char* dst = Ring + slot*32768 + w*4096 + lane*16;
#pragma unroll
        for (int i = 0; i < 4; ++i)
            __builtin_amdgcn_global_load_lds(
                (const __attribute__((address_space(1))) uint32*)(src + i*1024),
                (__attribute__((address_space(3))) uint32*)(dst + i*1024), 16, 0, 0);
    };
    auto stage_x = [&](int tt) {
        if (w < 7) {
            const char* s0 = xsrc + xo0 + (size_t)tt*224;
            const char* s1 = xsrc + xo1 + (size_t)tt*224;
            float* d0 = Xf + (2*w)*256 + lane*4;
            float* d1 = Xf + (2*w+1)*256 + lane*4;
            __builtin_amdgcn_global_load_lds((const __attribute__((address_space(1))) uint32*)s0,
                                             (__attribute__((address_space(3))) uint32*)d0, 16, 0, 0);
            __builtin_amdgcn_global_load_lds((const __attribute__((address_space(1))) uint32*)s1,
                                             (__attribute__((address_space(3))) uint32*)d1, 16, 0, 0);
        } else {   // keep vmcnt uniform across waves
            const char* s0 = xsrc + lane*16;
            __builtin_amdgcn_global_load_lds((const __attribute__((address_space(1))) uint32*)s0,
                                             (__attribute__((address_space(3))) uint32*)(Xd + lane*16), 16, 0, 0);
            __builtin_amdgcn_global_load_lds((const __attribute__((address_space(1))) uint32*)(s0 + 1024),
                                             (__attribute__((address_space(3))) uint32*)(Xd + 1024 + lane*16), 16, 0, 0);
        }
    };
    auto conv_x = [&](int buf) {        // Xf (f32) -> Xa[buf] fp8, swizzled granules
        int xr = tid >> 3, xs = tid & 7;   // row, granule
        uint32 lo = 0u, hi = 0u;
        if (xs < 7) {
            const float* xf = Xf + xr*56 + xs*8;
            f32x4 a = *reinterpret_cast<const f32x4*>(xf);
            f32x4 b = *reinterpret_cast<const f32x4*>(xf + 4);
            lo = __builtin_amdgcn_cvt_pk_fp8_f32(a[0], a[1], 0, false);
            lo = __builtin_amdgcn_cvt_pk_fp8_f32(a[2], a[3], lo, true);
            hi = __builtin_amdgcn_cvt_pk_fp8_f32(b[0], b[1], 0, false);
            hi = __builtin_amdgcn_cvt_pk_fp8_f32(b[2], b[3], hi, true);
        }
        uint32* p = reinterpret_cast<uint32*>(Xa + buf*4096 + xr*64 + ((xs ^ (xr & 7)) << 3));
        p[0] = lo; p[1] = hi;
    };

    // ---- prologue: x0 + units 0,1,2; zero Ah[0]; convert x0 -> Xa[0] ----
    stage_x(0);
    stage_w(0, 0); stage_w(1, 1); stage_w(2, 2);
    for (int i = tid; i < 4096; i += 512)
        reinterpret_cast<uint32*>(Ah)[i] = 0u;
    asm volatile("s_waitcnt vmcnt(0)" ::: "memory");
    __builtin_amdgcn_s_barrier();
    conv_x(0);
    asm volatile("s_waitcnt lgkmcnt(0)" ::: "memory");
    __builtin_amdgcn_s_barrier();

    f32x4 cst[4][2];                    // c state [rt][ht]
    f32x4 hv[4][2];                     // h(t), carried to epilogue
#pragma unroll
    for (int rt = 0; rt < 4; ++rt)
#pragma unroll
        for (int ht = 0; ht < 2; ++ht) cst[rt][ht] = (f32x4){0.f,0.f,0.f,0.f};

    int sl = 0;                         // ring slot of current unit (continuous mod 3)
#pragma unroll 1
    for (int t = 0; t < 96; ++t) {
        const int par = t & 1, nxt = par ^ 1;
        f32x4 acc[4][2][4];             // [rt][ht][q]
#pragma unroll
        for (int rt = 0; rt < 4; ++rt)
#pragma unroll
            for (int ht = 0; ht < 2; ++ht)
#pragma unroll
                for (int q = 0; q < 4; ++q)
                    acc[rt][ht][q] = bias[ht][q];

#pragma unroll 1
        for (int c = 0; c < 10; ++c) {
            // counted wait for unit c: phases 1-3 carry the 2 x-loads in the queue
            if (c >= 1 && c <= 3) asm volatile("s_waitcnt vmcnt(10)" ::: "memory");
            else                  asm volatile("s_waitcnt vmcnt(8)"  ::: "memory");

            const char* wb = Ring + sl*32768 + w*4096 + lane*16;
            ll_t Af[8];
#pragma unroll
            for (int j = 0; j < 4; ++j) {
                ll2 pr = *reinterpret_cast<const ll2*>(wb + j*1024);
                Af[2*j]   = pr.x;
                Af[2*j+1] = pr.y;
            }
            ll_t Bv[4];
            if (c < 2) {
#pragma unroll
                for (int rt = 0; rt < 4; ++rt)
                    Bv[rt] = *reinterpret_cast<const ll_t*>(
                        Xa + par*4096 + xbase_o[rt] + (((c*4 + l4q) ^ hswz[rt]) << 3));
            } else {
#pragma unroll
                for (int rt = 0; rt < 4; ++rt)
                    Bv[rt] = *reinterpret_cast<const ll_t*>(
                        Ah + par*16384 + hbase[rt] + (((c-2) ^ hswz[rt]) << 5));
            }
#pragma unroll
            for (int ht = 0; ht < 2; ++ht)
#pragma unroll
                for (int q = 0; q < 4; ++q) {
                    ll_t A = Af[ht*4 + q];
#pragma unroll
                    for (int rt = 0; rt < 4; ++rt)
                        acc[rt][ht][q] = __builtin_amdgcn_mfma_f32_16x16x32_fp8_fp8(
                            A, Bv[rt], acc[rt][ht][q], 0, 0, 0);
                }
            // issue-after-consume: unit c+3 reuses the slot just read
            {
                int u3 = c + 3; if (u3 >= 10) u3 -= 10;
                stage_w(sl, u3);
            }
            if (c == 0) stage_x(t < 95 ? t + 1 : 95);
            sl = sl + 1; if (sl >= 3) sl -= 3;
        }

        // ---- gates -> c, h (hw-rate transcendentals; thread-local) ----
#pragma unroll
        for (int rt = 0; rt < 4; ++rt)
#pragma unroll
            for (int ht = 0; ht < 2; ++ht)
#pragma unroll
                for (int e = 0; e < 4; ++e) {
                    float ig = sigmoid_hw(acc[rt][ht][0][e]);
                    float fg = sigmoid_hw(acc[rt][ht][1][e]);
                    float gt = tanh_hw  (acc[rt][ht][2][e]);
                    float og = sigmoid_hw(acc[rt][ht][3][e]);
                    float cn = fg * cst[rt][ht][e] + ig * gt;
                    cst[rt][ht][e] = cn;
                    hv[rt][ht][e] = og * tanh_hw(cn);
                }

        if (t < 95) {
            // h(t) -> Ah[nxt] (swizzled b32 stores); x(t+1) -> Xa[nxt]
#pragma unroll
            for (int rt = 0; rt < 4; ++rt)
#pragma unroll
                for (int ht = 0; ht < 2; ++ht) {
                    uint32 pk = __builtin_amdgcn_cvt_pk_fp8_f32(hv[rt][ht][0], hv[rt][ht][1], 0, false);
                    pk = __builtin_amdgcn_cvt_pk_fp8_f32(hv[rt][ht][2], hv[rt][ht][3], pk, true);
                    int row = rt*16 + l15;
                    int g   = 4*w + 2*ht + (l4q >> 1);
                    *reinterpret_cast<uint32*>(
                        Ah + nxt*16384 + row*256 + ((g ^ ((row & 7) << 2)) << 3) + 4*(l4q & 1)) = pk;
                }
            asm volatile("s_waitcnt vmcnt(12)" ::: "memory");   // x(t+1) landed in Xf
            conv_x(nxt);
            asm volatile("s_waitcnt lgkmcnt(0)" ::: "memory");
            __builtin_amdgcn_s_barrier();       // the ONE barrier: writes visible
        }
    }

    // ---- epilogue: out[row] += ah . h_T[row] ----
    {
        float part[4];
#pragma unroll
        for (int rt = 0; rt < 4; ++rt) {
            float s = 0.f;
#pragma unroll
            for (int ht = 0; ht < 2; ++ht)
#pragma unroll
                for (int e = 0; e < 4; ++e)
                    s += ahv[ht][e] * hv[rt][ht][e];
            s += __shfl_xor(s, 16);
            s += __shfl_xor(s, 32);
            part[rt] = s;
        }
        __builtin_amdgcn_s_barrier();
        asm volatile("s_waitcnt vmcnt(0)" ::: "memory");   // drain tail prefetches before Ring reuse
        float* sc = reinterpret_cast<float*>(Ring);
        if (l4q == 0)
#pragma unroll
            for (int rt = 0; rt < 4; ++rt)
                sc[w*64 + rt*16 + l15] = part[rt];
        asm volatile("s_waitcnt lgkmcnt(0)" ::: "memory");
        __builtin_amdgcn_s_barrier();
        if (tid < 64) {
            float s = 0.f;
#pragma unroll
            for (int wv = 0; wv < 8; ++wv) s += sc[wv*64 + tid];
            out[row0 + tid] += s;
        }
    }
}

// ---------------- launch ----------------
extern "C" void kernel_launch(void* const* d_in, const int* in_sizes, int n_in,
                              void* d_out, int out_size, void* d_ws, size_t ws_size,
                              hipStream_t stream) {
    const float* spatial  = (const float*)d_in[0];
    const float* temporal = (const float*)d_in[1];
    const float* sl_w = (const float*)d_in[2];  const float* sl_b = (const float*)d_in[3];
    const float* st_w = (const float*)d_in[4];  const float* st_b = (const float*)d_in[5];
    const float* seg_w = (const float*)d_in[6]; const float* seg_b = (const float*)d_in[7];
    const float* l1_w = (const float*)d_in[8];  const float* l1_b = (const float*)d_in[9];
    const float* l2_w = (const float*)d_in[10]; const float* l2_b = (const float*)d_in[11];
    const float* w_ih = (const float*)d_in[12]; const float* b_ih = (const float*)d_in[13];
    const float* w_hh = (const float*)d_in[14]; const float* b_hh = (const float*)d_in[15];
    const float* l4_w = (const float*)d_in[16]; const float* l4_b = (const float*)d_in[17];
    const float* l5_w = (const float*)d_in[18]; const float* l5_b = (const float*)d_in[19];
    const float* l6_w = (const float*)d_in[20]; const float* l6_b = (const float*)d_in[21];
    const float* l7_w = (const float*)d_in[22]; const float* l7_b = (const float*)d_in[23];

    char* ws = (char*)d_ws;
    float*  wsp   = (float*)(ws + WS_WSP);
    float*  ah    = (float*)(ws + WS_AH);
    float*  u527  = (float*)(ws + WS_U527);
    float*  biasT = (float*)(ws + WS_BIAS);
    float*  biasg = (float*)(ws + WS_BIASG);
    uint8*  wcq   = (uint8*)(ws + WS_WC);

    float* out = (float*)d_out;

    hipLaunchKernelGGL(k_head, dim3(1), dim3(512), 0, stream,
                       sl_w, sl_b, st_w, st_b, seg_b, l1_w, l1_b, l2_w, l2_b,
                       l4_w, l4_b, l5_w, l5_b, l6_w, l6_b, l7_w, l7_b,
                       wsp, ah, u527, biasT);
    hipLaunchKernelGGL(k_seg, dim3(5), dim3(256), 0, stream, seg_w, u527, wsp);
    hipLaunchKernelGGL(k_wcq, dim3(1280), dim3(256), 0, stream,
                       w_ih, b_ih, w_hh, b_hh, wcq, biasg);
    hipLaunchKernelGGL(k_spatial, dim3(16384/4), dim3(256), 0, stream,
                       spatial, wsp, biasT, out);
    hipLaunchKernelGGL(k_lstm, dim3(256), dim3(512), 0, stream,
                       temporal, wcq, biasg, ah, out);
}